// Round 4
// baseline (452.675 us; speedup 1.0000x reference)
//
#include <hip/hip_runtime.h>
#include <hip/hip_bf16.h>
#include <math.h>

#define NEG 0.2f
#define BNEPS 1e-5f
#define NGRAPH 64
#define SCAN_CHUNK 2048
#define POOL_BLOCKS 256

typedef short bf16x8 __attribute__((ext_vector_type(8)));            // 8 bf16 (4 VGPRs)
typedef float f32x4  __attribute__((ext_vector_type(4)));            // MFMA accumulator
typedef float f32x2  __attribute__((ext_vector_type(2)));            // fp8 cvt result

__device__ __forceinline__ float bf2f(unsigned short u) {
    return __uint_as_float(((unsigned)u) << 16);
}
__device__ __forceinline__ short f2bf(float f) {
    return (short)__bfloat16_as_ushort(__float2bfloat16(f));
}
__device__ __forceinline__ unsigned char f2fp8(float f) {
    // OCP e4m3 on gfx950; pack (f,f) and take low byte
    int pk = __builtin_amdgcn_cvt_pk_fp8_f32(f, f, 0, false);
    return (unsigned char)(pk & 0xFF);
}

// ---------- init: zero counts, pool accs, gstart; block 1: u/v = W_h @ att ----------
__global__ __launch_bounds__(256)
void init_kernel(const int* __restrict__ batch, int N,
                 int* __restrict__ counts, int* __restrict__ gstart,
                 float* __restrict__ hg_acc, float* __restrict__ wsum_acc,
                 const float* __restrict__ convs_W,
                 const float* __restrict__ convs_as, const float* __restrict__ convs_ad,
                 float* __restrict__ uv)
{
    int idx = blockIdx.x * 256 + threadIdx.x;
    for (int i = idx; i < N; i += gridDim.x * 256) counts[i] = 0;
    if (blockIdx.x == 0) {
        int t = threadIdx.x;
        for (int i = t; i < NGRAPH * 64; i += 256) hg_acc[i] = 0.f;
        if (t < NGRAPH) wsum_acc[t] = 0.f;
        if (t <= NGRAPH) {
            int lo = 0, hi = N;
            while (lo < hi) {
                int mid = (lo + hi) >> 1;
                if (batch[mid] < t) lo = mid + 1; else hi = mid;
            }
            gstart[t] = lo;
        }
    }
    if (blockIdx.x == 1) {
        // uv layout: u[2][4][64] then v[2][4][64]
        int t = threadIdx.x;
        int h = t >> 6, k = t & 63;
        for (int i = 0; i < 2; ++i) {
            const float* Wr  = convs_W + (size_t)i * 64 * 256 + k * 256 + h * 64;
            const float* av  = convs_as + i * 256 + h * 64;
            const float* dv  = convs_ad + i * 256 + h * 64;
            float su = 0.f, sv = 0.f;
            for (int c = 0; c < 64; ++c) { su += Wr[c] * av[c]; sv += Wr[c] * dv[c]; }
            uv[i * 256 + h * 64 + k]       = su;
            uv[512 + i * 256 + h * 64 + k] = sv;
        }
    }
}

// ---------- MFMA bf16 GEMM for layer-0 xh: C8[M,256] = fp8(A @ W) + att dots ----------
__global__ __launch_bounds__(256)
void gemm_xh_mfma(const float* __restrict__ A, int lda,
                  const float* __restrict__ W, int Nc, int M, int K,
                  const float* __restrict__ att_s, const float* __restrict__ att_d,
                  float* __restrict__ as_out, float* __restrict__ ad_out,
                  unsigned char* __restrict__ C8)
{
    __shared__ short Wt[64 * 136];           // max K=128 -> KP=136
    const int KP = K + 8;
    int tid  = threadIdx.x;
    int lane = tid & 63, wave = tid >> 6;
    int row0 = blockIdx.x * 64;
    int colb = blockIdx.y * 64;
    int c15 = lane & 15, q = lane >> 4;

    {
        int n = tid & 63;
        for (int k = tid >> 6; k < K; k += 4)
            Wt[n * KP + k] = f2bf(W[(size_t)k * Nc + colb + n]);
    }
    __syncthreads();

    int row = row0 + wave * 16 + c15;
    bool rok = row < M;
    const float* arow = A + (size_t)row * lda + q * 8;

    f32x4 acc[4];
    #pragma unroll
    for (int st = 0; st < 4; ++st) acc[st] = (f32x4){0.f, 0.f, 0.f, 0.f};

    for (int k0 = 0; k0 < K; k0 += 32) {
        bf16x8 av;
        if (rok) {
            float4 a0 = *(const float4*)(arow + k0);
            float4 a1 = *(const float4*)(arow + k0 + 4);
            av[0] = f2bf(a0.x); av[1] = f2bf(a0.y); av[2] = f2bf(a0.z); av[3] = f2bf(a0.w);
            av[4] = f2bf(a1.x); av[5] = f2bf(a1.y); av[6] = f2bf(a1.z); av[7] = f2bf(a1.w);
        } else {
            av = (bf16x8){0,0,0,0,0,0,0,0};
        }
        #pragma unroll
        for (int st = 0; st < 4; ++st) {
            bf16x8 bv = *(const bf16x8*)(Wt + (st * 16 + c15) * KP + k0 + q * 8);
            acc[st] = __builtin_amdgcn_mfma_f32_16x16x32_bf16(av, bv, acc[st], 0, 0, 0);
        }
    }

    #pragma unroll
    for (int r = 0; r < 4; ++r) {
        int orow = row0 + wave * 16 + q * 4 + r;
        if (orow >= M) continue;
        unsigned char* cb = C8 + (size_t)orow * 256 + colb + c15;
        #pragma unroll
        for (int st = 0; st < 4; ++st)
            cb[st * 16] = f2fp8(acc[st][r]);
    }
    float sa[4], da[4];
    #pragma unroll
    for (int st = 0; st < 4; ++st) {
        sa[st] = att_s[colb + st * 16 + c15];
        da[st] = att_d[colb + st * 16 + c15];
    }
    #pragma unroll
    for (int r = 0; r < 4; ++r) {
        float ps = acc[0][r] * sa[0] + acc[1][r] * sa[1] + acc[2][r] * sa[2] + acc[3][r] * sa[3];
        float pd = acc[0][r] * da[0] + acc[1][r] * da[1] + acc[2][r] * da[2] + acc[3][r] * da[3];
        #pragma unroll
        for (int o = 1; o < 16; o <<= 1) {
            ps += __shfl_xor(ps, o);
            pd += __shfl_xor(pd, o);
        }
        int orow = row0 + wave * 16 + q * 4 + r;
        if (c15 == 0 && orow < M) {
            as_out[orow * 4 + blockIdx.y] = ps;
            ad_out[orow * 4 + blockIdx.y] = pd;
        }
    }
}

// ---------- MFMA bf16 GEMM, Nc=64 (pre0 / jump) ----------
__global__ __launch_bounds__(256)
void gemm_n64_mfma(const void* __restrict__ Araw, int lda, int a_is_bf16,
                   const float* __restrict__ W, int w_gat, int M, int K,
                   const float* __restrict__ bias, float scale,
                   float* __restrict__ C, int ldc, int mode,
                   const float* __restrict__ bn_g, const float* __restrict__ bn_b,
                   const float* __restrict__ bn_m, const float* __restrict__ bn_v,
                   const float* __restrict__ resid, int ldr,
                   unsigned char* __restrict__ h8_out,
                   const float* __restrict__ u, const float* __restrict__ v,
                   float* __restrict__ as_out, float* __restrict__ ad_out,
                   const float* __restrict__ attW, const float* __restrict__ attb,
                   float* __restrict__ wout)
{
    __shared__ short Wt[64 * 264];           // max K=256 -> KP=264
    const int KP = K + 8;
    int tid  = threadIdx.x;
    int lane = tid & 63, wave = tid >> 6;
    int row0 = blockIdx.x * 64;
    int c15 = lane & 15, q = lane >> 4;

    {
        int n = tid & 63;
        for (int k = tid >> 6; k < K; k += 4) {
            int widx = w_gat ? ((k & 63) * 256 + (k >> 6) * 64 + n) : (k * 64 + n);
            Wt[n * KP + k] = f2bf(W[widx]);
        }
    }
    __syncthreads();

    int row = row0 + wave * 16 + c15;
    bool rok = row < M;

    f32x4 acc[4];
    #pragma unroll
    for (int st = 0; st < 4; ++st) acc[st] = (f32x4){0.f, 0.f, 0.f, 0.f};

    for (int k0 = 0; k0 < K; k0 += 32) {
        bf16x8 av;
        if (rok) {
            if (a_is_bf16) {
                av = *(const bf16x8*)((const unsigned short*)Araw
                                      + (size_t)row * lda + k0 + q * 8);
            } else {
                const float* ap = (const float*)Araw + (size_t)row * lda + k0 + q * 8;
                float4 a0 = *(const float4*)ap;
                float4 a1 = *(const float4*)(ap + 4);
                av[0] = f2bf(a0.x); av[1] = f2bf(a0.y); av[2] = f2bf(a0.z); av[3] = f2bf(a0.w);
                av[4] = f2bf(a1.x); av[5] = f2bf(a1.y); av[6] = f2bf(a1.z); av[7] = f2bf(a1.w);
            }
        } else {
            av = (bf16x8){0,0,0,0,0,0,0,0};
        }
        #pragma unroll
        for (int st = 0; st < 4; ++st) {
            bf16x8 bv = *(const bf16x8*)(Wt + (st * 16 + c15) * KP + k0 + q * 8);
            acc[st] = __builtin_amdgcn_mfma_f32_16x16x32_bf16(av, bv, acc[st], 0, 0, 0);
        }
    }

    #pragma unroll
    for (int st = 0; st < 4; ++st) {
        int col = st * 16 + c15;
        float bs = bias ? bias[col] : 0.f;
        float sg = 1.f, sb = 0.f;
        if (mode == 1) {
            sg = bn_g[col] / sqrtf(bn_v[col] + BNEPS);
            sb = bn_b[col] - bn_m[col] * sg;
        }
        #pragma unroll
        for (int r = 0; r < 4; ++r) {
            int orow = row0 + wave * 16 + q * 4 + r;
            if (orow >= M) continue;
            float vvv = acc[st][r] * scale + bs;
            if (mode == 1) {
                vvv = vvv * sg + sb;
                vvv = vvv > 0.f ? vvv : __expf(vvv) - 1.f;
            }
            if (resid) vvv += resid[(size_t)orow * ldr + col];
            acc[st][r] = vvv;
            C[(size_t)orow * ldc + col] = vvv;
        }
    }

    if (h8_out) {
        #pragma unroll
        for (int r = 0; r < 4; ++r) {
            int orow = row0 + wave * 16 + q * 4 + r;
            if (orow >= M) continue;
            unsigned char* hb = h8_out + (size_t)orow * 64 + c15;
            #pragma unroll
            for (int st = 0; st < 4; ++st)
                hb[st * 16] = f2fp8(acc[st][r]);
        }
    }

    if (u) {
        float uu[4][4], vv2[4][4];
        #pragma unroll
        for (int h = 0; h < 4; ++h)
            #pragma unroll
            for (int st = 0; st < 4; ++st) {
                uu[h][st]  = u[h * 64 + st * 16 + c15];
                vv2[h][st] = v[h * 64 + st * 16 + c15];
            }
        #pragma unroll
        for (int r = 0; r < 4; ++r) {
            int orow = row0 + wave * 16 + q * 4 + r;
            float pv[8];
            #pragma unroll
            for (int h = 0; h < 4; ++h) {
                pv[h]     = acc[0][r] * uu[h][0] + acc[1][r] * uu[h][1]
                          + acc[2][r] * uu[h][2] + acc[3][r] * uu[h][3];
                pv[4 + h] = acc[0][r] * vv2[h][0] + acc[1][r] * vv2[h][1]
                          + acc[2][r] * vv2[h][2] + acc[3][r] * vv2[h][3];
            }
            #pragma unroll
            for (int j = 0; j < 4; ++j) {
                float send = (c15 & 8) ? pv[j] : pv[j + 4];
                float keep = (c15 & 8) ? pv[j + 4] : pv[j];
                pv[j] = keep + __shfl_xor(send, 8);
            }
            #pragma unroll
            for (int j = 0; j < 2; ++j) {
                float send = (c15 & 4) ? pv[j] : pv[j + 2];
                float keep = (c15 & 4) ? pv[j + 2] : pv[j];
                pv[j] = keep + __shfl_xor(send, 4);
            }
            {
                float send = (c15 & 2) ? pv[0] : pv[1];
                float keep = (c15 & 2) ? pv[1] : pv[0];
                pv[0] = keep + __shfl_xor(send, 2);
            }
            pv[0] += __shfl_xor(pv[0], 1);
            if ((c15 & 1) == 0 && orow < M) {
                int jj = c15 >> 1;
                if (jj < 4) as_out[orow * 4 + jj] = pv[0];
                else        ad_out[orow * 4 + (jj - 4)] = pv[0];
            }
        }
    }

    if (wout) {
        float sa[4];
        #pragma unroll
        for (int st = 0; st < 4; ++st) sa[st] = attW[st * 16 + c15];
        float ab = attb[0];
        #pragma unroll
        for (int r = 0; r < 4; ++r) {
            float ps = acc[0][r] * sa[0] + acc[1][r] * sa[1]
                     + acc[2][r] * sa[2] + acc[3][r] * sa[3];
            #pragma unroll
            for (int o = 1; o < 16; o <<= 1) ps += __shfl_xor(ps, o);
            int orow = row0 + wave * 16 + q * 4 + r;
            if (c15 == 0 && orow < M) wout[orow] = __expf(ps + ab);
        }
    }
}

// ---------- fused layers 1-2: per-block aggregate z into LDS + stacked-W MFMA ----------
// Block = 64 nodes. Phase A: each wave aggregates 16 nodes (64B fp8 gather, per-head
// normalized) into zbuf LDS. Phase B: K=256 GEMM (W staged in two K=128 halves).
// Epilogue: BN+ELU+resid, optional fp8 h snapshot + next-layer as/ad logits.
__global__ __launch_bounds__(256)
void agg_gemm_z(const int* __restrict__ rowptr, const int* __restrict__ csr_src,
                const float* __restrict__ as_n, const float* __restrict__ ad_n,
                const unsigned char* __restrict__ hsrc,
                const float* __restrict__ W,           // convs_W slice, stacked layout
                int M,
                const float* __restrict__ bias, float scale,
                float* __restrict__ C, int ldc,
                const float* __restrict__ bn_g, const float* __restrict__ bn_b,
                const float* __restrict__ bn_m, const float* __restrict__ bn_v,
                const float* __restrict__ resid, int ldr,
                unsigned char* __restrict__ h8_out,
                const float* __restrict__ u, const float* __restrict__ v,
                float* __restrict__ as_out, float* __restrict__ ad_out)
{
    __shared__ short zbuf[64 * 264];   // 64 rows x 256 bf16, pad 8 -> 2-way-free reads
    __shared__ short Wt[64 * 136];     // one K=128 half of W
    int tid  = threadIdx.x;
    int lane = tid & 63, wave = tid >> 6;
    int row0 = blockIdx.x * 64;
    int h = lane >> 4, li = lane & 15, grp = lane & 48;
    int c15 = lane & 15, q = lane >> 4;
    unsigned laneoff = (unsigned)(li * 4);

    // ---- phase A: aggregate 16 nodes per wave into zbuf ----
    for (int i = 0; i < 16; ++i) {
        int node = row0 + wave * 16 + i;
        int nl = wave * 16 + i;
        float4 acc = make_float4(0.f, 0.f, 0.f, 0.f);
        float wsum = 0.f;
        if (node < M) {
            float adh = ad_n[node * 4 + h];
            int e0 = rowptr[node], e1 = rowptr[node + 1];
            for (int base = e0; base < e1; base += 16) {
                int cnt = e1 - base; if (cnt > 16) cnt = 16;
                int s = 0; float w = 0.f;
                if (li < cnt) {
                    s = csr_src[base + li];
                    float l = as_n[s * 4 + h] + adh;
                    l = fmaxf(l, NEG * l);
                    w = __expf(l);
                }
                int k = 0;
                for (; k + 3 < cnt; k += 4) {
                    float w0 = __shfl(w, grp + k),     w1 = __shfl(w, grp + k + 1);
                    float w2 = __shfl(w, grp + k + 2), w3 = __shfl(w, grp + k + 3);
                    int s0 = __shfl(s, grp + k),       s1 = __shfl(s, grp + k + 1);
                    int s2 = __shfl(s, grp + k + 2),   s3 = __shfl(s, grp + k + 3);
                    unsigned x0 = *(const unsigned*)(hsrc + ((unsigned)s0 * 64u + laneoff));
                    unsigned x1 = *(const unsigned*)(hsrc + ((unsigned)s1 * 64u + laneoff));
                    unsigned x2 = *(const unsigned*)(hsrc + ((unsigned)s2 * 64u + laneoff));
                    unsigned x3 = *(const unsigned*)(hsrc + ((unsigned)s3 * 64u + laneoff));
                    f32x2 l0 = __builtin_amdgcn_cvt_pk_f32_fp8((int)x0, false);
                    f32x2 h0 = __builtin_amdgcn_cvt_pk_f32_fp8((int)x0, true);
                    f32x2 l1 = __builtin_amdgcn_cvt_pk_f32_fp8((int)x1, false);
                    f32x2 h1 = __builtin_amdgcn_cvt_pk_f32_fp8((int)x1, true);
                    f32x2 l2 = __builtin_amdgcn_cvt_pk_f32_fp8((int)x2, false);
                    f32x2 h2 = __builtin_amdgcn_cvt_pk_f32_fp8((int)x2, true);
                    f32x2 l3 = __builtin_amdgcn_cvt_pk_f32_fp8((int)x3, false);
                    f32x2 h3 = __builtin_amdgcn_cvt_pk_f32_fp8((int)x3, true);
                    acc.x += w0 * l0.x; acc.y += w0 * l0.y; acc.z += w0 * h0.x; acc.w += w0 * h0.y;
                    acc.x += w1 * l1.x; acc.y += w1 * l1.y; acc.z += w1 * h1.x; acc.w += w1 * h1.y;
                    acc.x += w2 * l2.x; acc.y += w2 * l2.y; acc.z += w2 * h2.x; acc.w += w2 * h2.y;
                    acc.x += w3 * l3.x; acc.y += w3 * l3.y; acc.z += w3 * h3.x; acc.w += w3 * h3.y;
                    wsum += (w0 + w1) + (w2 + w3);
                }
                for (; k < cnt; ++k) {
                    float wk = __shfl(w, grp + k);
                    int sk = __shfl(s, grp + k);
                    unsigned xv = *(const unsigned*)(hsrc + ((unsigned)sk * 64u + laneoff));
                    f32x2 lo = __builtin_amdgcn_cvt_pk_f32_fp8((int)xv, false);
                    f32x2 hi = __builtin_amdgcn_cvt_pk_f32_fp8((int)xv, true);
                    acc.x += wk * lo.x; acc.y += wk * lo.y;
                    acc.z += wk * hi.x; acc.w += wk * hi.y;
                    wsum += wk;
                }
            }
        }
        float rw = (wsum > 0.f) ? 1.f / wsum : 0.f;
        ushort4 pk;
        pk.x = (unsigned short)f2bf(acc.x * rw);
        pk.y = (unsigned short)f2bf(acc.y * rw);
        pk.z = (unsigned short)f2bf(acc.z * rw);
        pk.w = (unsigned short)f2bf(acc.w * rw);
        *(ushort4*)((unsigned short*)zbuf + nl * 264 + lane * 4) = pk;
    }

    // ---- phase B: GEMM, K=256 in two halves ----
    f32x4 acc2[4];
    #pragma unroll
    for (int st = 0; st < 4; ++st) acc2[st] = (f32x4){0.f, 0.f, 0.f, 0.f};

    for (int kh = 0; kh < 2; ++kh) {
        __syncthreads();
        {
            int n = tid & 63;
            for (int k = tid >> 6; k < 128; k += 4) {
                int kk = kh * 128 + k;
                Wt[n * 136 + k] = f2bf(W[(kk & 63) * 256 + (kk >> 6) * 64 + n]);
            }
        }
        __syncthreads();
        const unsigned short* zb = (const unsigned short*)zbuf;
        for (int k0 = 0; k0 < 128; k0 += 32) {
            bf16x8 av = *(const bf16x8*)(zb + (wave * 16 + c15) * 264 + kh * 128 + k0 + q * 8);
            #pragma unroll
            for (int st = 0; st < 4; ++st) {
                bf16x8 bv = *(const bf16x8*)(Wt + (st * 16 + c15) * 136 + k0 + q * 8);
                acc2[st] = __builtin_amdgcn_mfma_f32_16x16x32_bf16(av, bv, acc2[st], 0, 0, 0);
            }
        }
    }

    // ---- epilogue: BN + ELU + resid ----
    #pragma unroll
    for (int st = 0; st < 4; ++st) {
        int col = st * 16 + c15;
        float bs = bias[col];
        float sg = bn_g[col] / sqrtf(bn_v[col] + BNEPS);
        float sb = bn_b[col] - bn_m[col] * sg;
        #pragma unroll
        for (int r = 0; r < 4; ++r) {
            int orow = row0 + wave * 16 + q * 4 + r;
            if (orow >= M) continue;
            float vvv = acc2[st][r] * scale + bs;
            vvv = vvv * sg + sb;
            vvv = vvv > 0.f ? vvv : __expf(vvv) - 1.f;
            vvv += resid[(size_t)orow * ldr + col];
            acc2[st][r] = vvv;
            C[(size_t)orow * ldc + col] = vvv;
        }
    }

    if (h8_out) {
        #pragma unroll
        for (int r = 0; r < 4; ++r) {
            int orow = row0 + wave * 16 + q * 4 + r;
            if (orow >= M) continue;
            unsigned char* hb = h8_out + (size_t)orow * 64 + c15;
            #pragma unroll
            for (int st = 0; st < 4; ++st)
                hb[st * 16] = f2fp8(acc2[st][r]);
        }
    }

    if (u) {
        float uu[4][4], vv2[4][4];
        #pragma unroll
        for (int hh = 0; hh < 4; ++hh)
            #pragma unroll
            for (int st = 0; st < 4; ++st) {
                uu[hh][st]  = u[hh * 64 + st * 16 + c15];
                vv2[hh][st] = v[hh * 64 + st * 16 + c15];
            }
        #pragma unroll
        for (int r = 0; r < 4; ++r) {
            int orow = row0 + wave * 16 + q * 4 + r;
            float pv[8];
            #pragma unroll
            for (int hh = 0; hh < 4; ++hh) {
                pv[hh]     = acc2[0][r] * uu[hh][0] + acc2[1][r] * uu[hh][1]
                           + acc2[2][r] * uu[hh][2] + acc2[3][r] * uu[hh][3];
                pv[4 + hh] = acc2[0][r] * vv2[hh][0] + acc2[1][r] * vv2[hh][1]
                           + acc2[2][r] * vv2[hh][2] + acc2[3][r] * vv2[hh][3];
            }
            #pragma unroll
            for (int j = 0; j < 4; ++j) {
                float send = (c15 & 8) ? pv[j] : pv[j + 4];
                float keep = (c15 & 8) ? pv[j + 4] : pv[j];
                pv[j] = keep + __shfl_xor(send, 8);
            }
            #pragma unroll
            for (int j = 0; j < 2; ++j) {
                float send = (c15 & 4) ? pv[j] : pv[j + 2];
                float keep = (c15 & 4) ? pv[j + 2] : pv[j];
                pv[j] = keep + __shfl_xor(send, 4);
            }
            {
                float send = (c15 & 2) ? pv[0] : pv[1];
                float keep = (c15 & 2) ? pv[1] : pv[0];
                pv[0] = keep + __shfl_xor(send, 2);
            }
            pv[0] += __shfl_xor(pv[0], 1);
            if ((c15 & 1) == 0 && orow < M) {
                int jj = c15 >> 1;
                if (jj < 4) as_out[orow * 4 + jj] = pv[0];
                else        ad_out[orow * 4 + (jj - 4)] = pv[0];
            }
        }
    }
}

// ---------- CSR build: histogram over dst ----------
__global__ __launch_bounds__(256)
void hist_kernel(const int* __restrict__ ei, int E, int N, int* __restrict__ counts)
{
    int e = blockIdx.x * blockDim.x + threadIdx.x;
    int Etot = E + N;
    if (e >= Etot) return;
    int d = (e < E) ? ei[E + e] : e - E;
    atomicAdd(&counts[d], 1);
}

// ---------- scan phase 1: per-block partial sums ----------
__global__ __launch_bounds__(256)
void scan_phase1(const int* __restrict__ counts, int N, int* __restrict__ blocksum)
{
    __shared__ int wsum[4];
    int tid = threadIdx.x, lane = tid & 63, wave = tid >> 6;
    int base = blockIdx.x * SCAN_CHUNK;
    int s = 0;
    #pragma unroll
    for (int j = 0; j < SCAN_CHUNK / 256; ++j) {
        int idx = base + tid + j * 256;
        if (idx < N) s += counts[idx];
    }
    #pragma unroll
    for (int o = 32; o; o >>= 1) s += __shfl_xor(s, o);
    if (lane == 0) wsum[wave] = s;
    __syncthreads();
    if (tid == 0) blocksum[blockIdx.x] = wsum[0] + wsum[1] + wsum[2] + wsum[3];
}

// ---------- scan phase 3 (merged with global prefix of block sums) ----------
__global__ __launch_bounds__(256)
void scan_phase3(const int* __restrict__ counts, int N, int nb,
                 const int* __restrict__ blocksum,
                 int* __restrict__ rowptr, int* __restrict__ cursor)
{
    __shared__ int wsum[4];
    __shared__ int pref[64];
    int tid = threadIdx.x, lane = tid & 63, wave = tid >> 6;

    if (wave == 0) {
        int v = (lane < nb) ? blocksum[lane] : 0;
        int incl = v;
        #pragma unroll
        for (int o = 1; o < 64; o <<= 1) {
            int t = __shfl_up(incl, o);
            if (lane >= o) incl += t;
        }
        pref[lane] = incl;
    }
    __syncthreads();
    int boff = blockIdx.x ? pref[blockIdx.x - 1] : 0;
    if (blockIdx.x == 0 && tid == 0) rowptr[N] = pref[nb - 1];

    int start = blockIdx.x * SCAN_CHUNK + tid * 8;
    int v[8];
    int s = 0;
    #pragma unroll
    for (int j = 0; j < 8; ++j) {
        v[j] = (start + j < N) ? counts[start + j] : 0;
        s += v[j];
    }
    int incl = s;
    #pragma unroll
    for (int o = 1; o < 64; o <<= 1) {
        int t = __shfl_up(incl, o);
        if (lane >= o) incl += t;
    }
    if (lane == 63) wsum[wave] = incl;
    __syncthreads();
    int woff = 0;
    #pragma unroll
    for (int w = 0; w < 4; ++w) if (w < wave) woff += wsum[w];
    int run = boff + woff + incl - s;
    #pragma unroll
    for (int j = 0; j < 8; ++j) {
        int idx = start + j;
        if (idx < N) { rowptr[idx] = run; cursor[idx] = run; }
        run += v[j];
    }
}

// ---------- CSR build: scatter ----------
__global__ __launch_bounds__(256)
void scatter_kernel(const int* __restrict__ ei, int E, int N,
                    int* __restrict__ cursor, int* __restrict__ csr_src)
{
    int e = blockIdx.x * blockDim.x + threadIdx.x;
    int Etot = E + N;
    if (e >= Etot) return;
    int s, d;
    if (e < E) { s = ei[e]; d = ei[E + e]; } else { s = d = e - E; }
    int pos = atomicAdd(&cursor[d], 1);
    csr_src[pos] = s;
}

// ---------- layer-0 GAT aggregation (fp8 256-ch message gather) ----------
__global__ __launch_bounds__(256)
void aggregate_kernel(const int* __restrict__ rowptr, const int* __restrict__ csr_src,
                      const float* __restrict__ as_n, const float* __restrict__ ad_n,
                      const unsigned char* __restrict__ xh8,
                      const float* __restrict__ bias,
                      unsigned short* __restrict__ outp, int N)
{
    int node = (blockIdx.x * blockDim.x + threadIdx.x) >> 6;
    int lane = threadIdx.x & 63;
    if (node >= N) return;
    int h = lane >> 4, li = lane & 15, grp = lane & 48;
    int e0 = rowptr[node], e1 = rowptr[node + 1];
    float adh = ad_n[node * 4 + h];
    unsigned laneoff = (unsigned)(lane * 4);   // 4 fp8 bytes per lane

    float4 acc = make_float4(0.f, 0.f, 0.f, 0.f);
    float wsum = 0.f;

    for (int base = e0; base < e1; base += 16) {
        int cnt = e1 - base; if (cnt > 16) cnt = 16;
        int s = 0; float w = 0.f;
        if (li < cnt) {
            s = csr_src[base + li];
            float l = as_n[s * 4 + h] + adh;
            l = fmaxf(l, NEG * l);
            w = __expf(l);
        }
        int k = 0;
        for (; k + 3 < cnt; k += 4) {
            float w0 = __shfl(w, grp + k),     w1 = __shfl(w, grp + k + 1);
            float w2 = __shfl(w, grp + k + 2), w3 = __shfl(w, grp + k + 3);
            int s0 = __shfl(s, grp + k),       s1 = __shfl(s, grp + k + 1);
            int s2 = __shfl(s, grp + k + 2),   s3 = __shfl(s, grp + k + 3);
            unsigned x0 = *(const unsigned*)(xh8 + ((unsigned)s0 * 256u + laneoff));
            unsigned x1 = *(const unsigned*)(xh8 + ((unsigned)s1 * 256u + laneoff));
            unsigned x2 = *(const unsigned*)(xh8 + ((unsigned)s2 * 256u + laneoff));
            unsigned x3 = *(const unsigned*)(xh8 + ((unsigned)s3 * 256u + laneoff));
            f32x2 l0 = __builtin_amdgcn_cvt_pk_f32_fp8((int)x0, false);
            f32x2 h0 = __builtin_amdgcn_cvt_pk_f32_fp8((int)x0, true);
            f32x2 l1 = __builtin_amdgcn_cvt_pk_f32_fp8((int)x1, false);
            f32x2 h1 = __builtin_amdgcn_cvt_pk_f32_fp8((int)x1, true);
            f32x2 l2 = __builtin_amdgcn_cvt_pk_f32_fp8((int)x2, false);
            f32x2 h2 = __builtin_amdgcn_cvt_pk_f32_fp8((int)x2, true);
            f32x2 l3 = __builtin_amdgcn_cvt_pk_f32_fp8((int)x3, false);
            f32x2 h3 = __builtin_amdgcn_cvt_pk_f32_fp8((int)x3, true);
            acc.x += w0 * l0.x; acc.y += w0 * l0.y; acc.z += w0 * h0.x; acc.w += w0 * h0.y;
            acc.x += w1 * l1.x; acc.y += w1 * l1.y; acc.z += w1 * h1.x; acc.w += w1 * h1.y;
            acc.x += w2 * l2.x; acc.y += w2 * l2.y; acc.z += w2 * h2.x; acc.w += w2 * h2.y;
            acc.x += w3 * l3.x; acc.y += w3 * l3.y; acc.z += w3 * h3.x; acc.w += w3 * h3.y;
            wsum += (w0 + w1) + (w2 + w3);
        }
        for (; k < cnt; ++k) {
            float wk = __shfl(w, grp + k);
            int sk = __shfl(s, grp + k);
            unsigned xv = *(const unsigned*)(xh8 + ((unsigned)sk * 256u + laneoff));
            f32x2 lo = __builtin_amdgcn_cvt_pk_f32_fp8((int)xv, false);
            f32x2 hi = __builtin_amdgcn_cvt_pk_f32_fp8((int)xv, true);
            acc.x += wk * lo.x; acc.y += wk * lo.y;
            acc.z += wk * hi.x; acc.w += wk * hi.y;
            wsum += wk;
        }
    }

    float rw = 1.f / wsum;
    float4 bs = *(const float4*)(bias + lane * 4);
    ushort4 pk;
    pk.x = (unsigned short)f2bf(acc.x * rw + bs.x);
    pk.y = (unsigned short)f2bf(acc.y * rw + bs.y);
    pk.z = (unsigned short)f2bf(acc.z * rw + bs.z);
    pk.w = (unsigned short)f2bf(acc.w * rw + bs.w);
    *(ushort4*)(outp + (size_t)node * 256 + lane * 4) = pk;
}

// ---------- pooling partial sums ----------
__global__ __launch_bounds__(256)
void pool_partial(const float* __restrict__ hjk, const float* __restrict__ w,
                  const int* __restrict__ batch, const int* __restrict__ gstart,
                  float* __restrict__ hg_acc, float* __restrict__ wsum_acc, int N)
{
    __shared__ float red[256];
    __shared__ float wred[4];
    int tid = threadIdx.x;
    int c = tid & 63, q = tid >> 6;
    int slab = (N + POOL_BLOCKS - 1) / POOL_BLOCKS;
    int n0 = blockIdx.x * slab;
    int n1 = n0 + slab; if (n1 > N) n1 = N;
    if (n0 >= n1) return;
    int g0 = batch[n0], g1 = batch[n1 - 1];

    for (int g = g0; g <= g1; ++g) {
        int s = gstart[g];     if (s < n0) s = n0;
        int e = gstart[g + 1]; if (e > n1) e = n1;
        float acc = 0.f, ws = 0.f;
        for (int n = s + q; n < e; n += 4) {
            float wn = w[n];
            acc += wn * hjk[(size_t)n * 64 + c];
            if (c == 0) ws += wn;
        }
        red[tid] = acc;
        if (c == 0) wred[q] = ws;
        __syncthreads();
        if (q == 0) {
            float v = red[c] + red[64 + c] + red[128 + c] + red[192 + c];
            if (v != 0.f) atomicAdd(&hg_acc[g * 64 + c], v);
            if (c == 0) {
                float t = wred[0] + wred[1] + wred[2] + wred[3];
                if (t != 0.f) atomicAdd(&wsum_acc[g], t);
            }
        }
        __syncthreads();
    }
}

// ---------- classifier head ----------
__global__ void cls_kernel(const float* __restrict__ hg_acc,
                           const float* __restrict__ wsum_acc,
                           const float* __restrict__ W1, const float* __restrict__ b1,
                           const float* __restrict__ W2, const float* __restrict__ b2,
                           float* __restrict__ out)
{
    int g = blockIdx.x, t = threadIdx.x;  // 32 threads
    __shared__ float z[32];
    __shared__ float h[64];
    float wsum = wsum_acc[g];
    float rw = (wsum > 0.f) ? 1.f / wsum : 0.f;
    h[t] = hg_acc[g * 64 + t] * rw;
    h[t + 32] = hg_acc[g * 64 + t + 32] * rw;
    __syncthreads();
    float acc = b1[t];
    for (int k = 0; k < 64; ++k) acc += h[k] * W1[k * 32 + t];
    z[t] = fmaxf(acc, 0.f);
    __syncthreads();
    if (t < 2) {
        float o = b2[t];
        for (int j = 0; j < 32; ++j) o += z[j] * W2[j * 2 + t];
        out[g * 2 + t] = o;
    }
}

extern "C" void kernel_launch(void* const* d_in, const int* in_sizes, int n_in,
                              void* d_out, int out_size, void* d_ws, size_t ws_size,
                              hipStream_t stream)
{
    const float* x        = (const float*)d_in[0];
    const int*   ei       = (const int*)d_in[1];
    const int*   batch    = (const int*)d_in[2];
    const float* conv0_W  = (const float*)d_in[3];
    const float* conv0_as = (const float*)d_in[4];
    const float* conv0_ad = (const float*)d_in[5];
    const float* conv0_b  = (const float*)d_in[6];
    const float* pre0_W   = (const float*)d_in[7];
    const float* pre0_b   = (const float*)d_in[8];
    const float* convs_W  = (const float*)d_in[9];
    const float* convs_as = (const float*)d_in[10];
    const float* convs_ad = (const float*)d_in[11];
    const float* convs_b  = (const float*)d_in[12];
    const float* bn_g     = (const float*)d_in[13];
    const float* bn_b     = (const float*)d_in[14];
    const float* bn_m     = (const float*)d_in[15];
    const float* bn_v     = (const float*)d_in[16];
    const float* jump_W   = (const float*)d_in[17];
    const float* jump_b   = (const float*)d_in[18];
    const float* att_W    = (const float*)d_in[19];
    const float* att_b    = (const float*)d_in[20];
    const float* cls_W1   = (const float*)d_in[21];
    const float* cls_b1   = (const float*)d_in[22];
    const float* cls_W2   = (const float*)d_in[23];
    const float* cls_b2   = (const float*)d_in[24];
    float* out = (float*)d_out;

    const int N = in_sizes[0] / 128;   // 50000
    const int E = in_sizes[1] / 2;     // 400000
    const int Etot = E + N;
    const int nb = (N + SCAN_CHUNK - 1) / SCAN_CHUNK;   // 25 <= 64

    // workspace layout
    float* ws      = (float*)d_ws;
    unsigned char* xh8      = (unsigned char*)ws;            // layer0: N*256 fp8; then h8a N*64 fp8 (aliased)
    unsigned short* h256_bf = (unsigned short*)ws + (size_t)N * 256;  // N*256 bf16 (L0 out_cat)
    float* repsAll = (float*)(h256_bf + (size_t)N * 256);   // N*192 f32
    float* as_n    = repsAll + (size_t)N * 192;             // N*4
    float* ad_n    = as_n + (size_t)N * 4;                  // N*4
    float* hjk     = ad_n + (size_t)N * 4;                  // N*64
    float* hg_acc  = hjk + (size_t)N * 64;                  // 64*64
    float* wsum_acc= hg_acc + NGRAPH * 64;                  // 64
    int*   rowptr  = (int*)(wsum_acc + NGRAPH);             // N+1
    int*   cursor  = rowptr + (N + 1);                      // N
    int*   counts  = cursor + N;                            // N
    int*   csr_src = counts + N;                            // Etot
    int*   gstart  = csr_src + Etot;                        // 65
    int*   blocksum = gstart + (NGRAPH + 1);                // 64
    float* uv      = (float*)(blocksum + 64);               // u[2][4][64]+v[2][4][64] = 1024
    float* as2     = uv + 1024;                             // N*4 (L2 logits)
    float* ad2     = as2 + (size_t)N * 4;                   // N*4
    unsigned char* h8b = (unsigned char*)(ad2 + (size_t)N * 4);  // N*64 fp8
    unsigned char* h8a = xh8;                               // N*64 fp8 (reuse xh8 region)
    float* wbuf    = as_n;  // reuse (free after L2 gather)

    dim3 blk(256);
    int node_wave_blocks = (N + 3) / 4;
    int edge_blocks      = (Etot + 255) / 256;
    int row_blocks       = (N + 63) / 64;

    // ---------------- init + CSR build ----------------
    init_kernel<<<64, blk, 0, stream>>>(batch, N, counts, gstart, hg_acc, wsum_acc,
                                        convs_W, convs_as, convs_ad, uv);
    hist_kernel<<<edge_blocks, blk, 0, stream>>>(ei, E, N, counts);
    scan_phase1<<<nb, blk, 0, stream>>>(counts, N, blocksum);
    scan_phase3<<<nb, blk, 0, stream>>>(counts, N, nb, blocksum, rowptr, cursor);
    scatter_kernel<<<edge_blocks, blk, 0, stream>>>(ei, E, N, cursor, csr_src);

    // ---------------- layer 0 ----------------
    {
        dim3 g1(row_blocks, 4);
        gemm_xh_mfma<<<g1, blk, 0, stream>>>(x, 128, conv0_W, 256, N, 128,
                                             conv0_as, conv0_ad, as_n, ad_n, xh8);
        aggregate_kernel<<<node_wave_blocks, blk, 0, stream>>>(
            rowptr, csr_src, as_n, ad_n, xh8, conv0_b, h256_bf, N);
        // pre0: h256 -> h1 (BN+ELU), fused: h8a snapshot + layer-1 as/ad logits
        gemm_n64_mfma<<<row_blocks, blk, 0, stream>>>(
            h256_bf, 256, 1, pre0_W, 0, N, 256, pre0_b, 1.f,
            repsAll, 192, 1, bn_g, bn_b, bn_m, bn_v,
            nullptr, 0, h8a, uv, uv + 512, as_n, ad_n,
            nullptr, nullptr, nullptr);
    }

    // ---------------- layer 1 (fused aggregate + GEMM) ----------------
    agg_gemm_z<<<row_blocks, blk, 0, stream>>>(
        rowptr, csr_src, as_n, ad_n, h8a,
        convs_W, N, convs_b, 0.25f,
        repsAll + 64, 192,
        bn_g + 64, bn_b + 64, bn_m + 64, bn_v + 64,
        repsAll, 192,
        h8b, uv + 256, uv + 512 + 256, as2, ad2);

    // ---------------- layer 2 (fused aggregate + GEMM) ----------------
    agg_gemm_z<<<row_blocks, blk, 0, stream>>>(
        rowptr, csr_src, as2, ad2, h8b,
        convs_W + (size_t)64 * 256, N, convs_b + 64, 0.25f,
        repsAll + 128, 192,
        bn_g + 128, bn_b + 128, bn_m + 128, bn_v + 128,
        repsAll + 64, 192,
        nullptr, nullptr, nullptr, nullptr, nullptr);

    // ---------------- JK projection + fused pool logits ----------------
    gemm_n64_mfma<<<row_blocks, blk, 0, stream>>>(
        repsAll, 192, 0, jump_W, 0, N, 192, jump_b, 1.f,
        hjk, 64, 0, nullptr, nullptr, nullptr, nullptr,
        nullptr, 0, nullptr, nullptr, nullptr, nullptr, nullptr,
        att_W, att_b, wbuf);

    // ---------------- pooling + classifier ----------------
    pool_partial<<<POOL_BLOCKS, blk, 0, stream>>>(hjk, wbuf, batch, gstart,
                                                  hg_acc, wsum_acc, N);
    cls_kernel<<<NGRAPH, 32, 0, stream>>>(hg_acc, wsum_acc, cls_W1, cls_b1,
                                          cls_W2, cls_b2, out);
}

// Round 5
// 433.356 us; speedup vs baseline: 1.0446x; 1.0446x over previous
//
#include <hip/hip_runtime.h>
#include <hip/hip_bf16.h>
#include <math.h>

#define NEG 0.2f
#define BNEPS 1e-5f
#define NGRAPH 64
#define SCAN_CHUNK 2048

typedef short bf16x8 __attribute__((ext_vector_type(8)));            // 8 bf16 (4 VGPRs)
typedef float f32x4  __attribute__((ext_vector_type(4)));            // MFMA accumulator
typedef float f32x2  __attribute__((ext_vector_type(2)));            // fp8 cvt result

__device__ __forceinline__ float bf2f(unsigned short u) {
    return __uint_as_float(((unsigned)u) << 16);
}
__device__ __forceinline__ short f2bf(float f) {
    return (short)__bfloat16_as_ushort(__float2bfloat16(f));
}
__device__ __forceinline__ unsigned char f2fp8(float f) {
    // OCP e4m3 on gfx950; pack (f,f) and take low byte
    int pk = __builtin_amdgcn_cvt_pk_fp8_f32(f, f, 0, false);
    return (unsigned char)(pk & 0xFF);
}

// ---------- init: zero counts, pool accs, gstart; block 1: u/v = W_h @ att ----------
__global__ __launch_bounds__(256)
void init_kernel(const int* __restrict__ batch, int N,
                 int* __restrict__ counts, int* __restrict__ gstart,
                 float* __restrict__ hg_acc, float* __restrict__ wsum_acc,
                 const float* __restrict__ convs_W,
                 const float* __restrict__ convs_as, const float* __restrict__ convs_ad,
                 float* __restrict__ uv)
{
    int idx = blockIdx.x * 256 + threadIdx.x;
    for (int i = idx; i < N; i += gridDim.x * 256) counts[i] = 0;
    if (blockIdx.x == 0) {
        int t = threadIdx.x;
        for (int i = t; i < NGRAPH * 64; i += 256) hg_acc[i] = 0.f;
        if (t < NGRAPH) wsum_acc[t] = 0.f;
        if (t <= NGRAPH) {
            int lo = 0, hi = N;
            while (lo < hi) {
                int mid = (lo + hi) >> 1;
                if (batch[mid] < t) lo = mid + 1; else hi = mid;
            }
            gstart[t] = lo;
        }
    }
    if (blockIdx.x == 1) {
        // uv layout: u[2][4][64] then v[2][4][64]
        int t = threadIdx.x;
        int h = t >> 6, k = t & 63;
        for (int i = 0; i < 2; ++i) {
            const float* Wr  = convs_W + (size_t)i * 64 * 256 + k * 256 + h * 64;
            const float* av  = convs_as + i * 256 + h * 64;
            const float* dv  = convs_ad + i * 256 + h * 64;
            float su = 0.f, sv = 0.f;
            for (int c = 0; c < 64; ++c) { su += Wr[c] * av[c]; sv += Wr[c] * dv[c]; }
            uv[i * 256 + h * 64 + k]       = su;
            uv[512 + i * 256 + h * 64 + k] = sv;
        }
    }
}

// ---------- MFMA bf16 GEMM for layer-0 xh: C8[M,256] = fp8(A @ W) + att dots ----------
__global__ __launch_bounds__(256)
void gemm_xh_mfma(const float* __restrict__ A, int lda,
                  const float* __restrict__ W, int Nc, int M, int K,
                  const float* __restrict__ att_s, const float* __restrict__ att_d,
                  float* __restrict__ as_out, float* __restrict__ ad_out,
                  unsigned char* __restrict__ C8)
{
    __shared__ short Wt[64 * 136];           // max K=128 -> KP=136
    const int KP = K + 8;
    int tid  = threadIdx.x;
    int lane = tid & 63, wave = tid >> 6;
    int row0 = blockIdx.x * 64;
    int colb = blockIdx.y * 64;
    int c15 = lane & 15, q = lane >> 4;

    {
        int n = tid & 63;
        for (int k = tid >> 6; k < K; k += 4)
            Wt[n * KP + k] = f2bf(W[(size_t)k * Nc + colb + n]);
    }
    __syncthreads();

    int row = row0 + wave * 16 + c15;
    bool rok = row < M;
    const float* arow = A + (size_t)row * lda + q * 8;

    f32x4 acc[4];
    #pragma unroll
    for (int st = 0; st < 4; ++st) acc[st] = (f32x4){0.f, 0.f, 0.f, 0.f};

    for (int k0 = 0; k0 < K; k0 += 32) {
        bf16x8 av;
        if (rok) {
            float4 a0 = *(const float4*)(arow + k0);
            float4 a1 = *(const float4*)(arow + k0 + 4);
            av[0] = f2bf(a0.x); av[1] = f2bf(a0.y); av[2] = f2bf(a0.z); av[3] = f2bf(a0.w);
            av[4] = f2bf(a1.x); av[5] = f2bf(a1.y); av[6] = f2bf(a1.z); av[7] = f2bf(a1.w);
        } else {
            av = (bf16x8){0,0,0,0,0,0,0,0};
        }
        #pragma unroll
        for (int st = 0; st < 4; ++st) {
            bf16x8 bv = *(const bf16x8*)(Wt + (st * 16 + c15) * KP + k0 + q * 8);
            acc[st] = __builtin_amdgcn_mfma_f32_16x16x32_bf16(av, bv, acc[st], 0, 0, 0);
        }
    }

    #pragma unroll
    for (int r = 0; r < 4; ++r) {
        int orow = row0 + wave * 16 + q * 4 + r;
        if (orow >= M) continue;
        unsigned char* cb = C8 + (size_t)orow * 256 + colb + c15;
        #pragma unroll
        for (int st = 0; st < 4; ++st)
            cb[st * 16] = f2fp8(acc[st][r]);
    }
    float sa[4], da[4];
    #pragma unroll
    for (int st = 0; st < 4; ++st) {
        sa[st] = att_s[colb + st * 16 + c15];
        da[st] = att_d[colb + st * 16 + c15];
    }
    #pragma unroll
    for (int r = 0; r < 4; ++r) {
        float ps = acc[0][r] * sa[0] + acc[1][r] * sa[1] + acc[2][r] * sa[2] + acc[3][r] * sa[3];
        float pd = acc[0][r] * da[0] + acc[1][r] * da[1] + acc[2][r] * da[2] + acc[3][r] * da[3];
        #pragma unroll
        for (int o = 1; o < 16; o <<= 1) {
            ps += __shfl_xor(ps, o);
            pd += __shfl_xor(pd, o);
        }
        int orow = row0 + wave * 16 + q * 4 + r;
        if (c15 == 0 && orow < M) {
            as_out[orow * 4 + blockIdx.y] = ps;
            ad_out[orow * 4 + blockIdx.y] = pd;
        }
    }
}

// ---------- MFMA bf16 GEMM, Nc=64 ----------
// w_gat=1: W is convs_W (64,256) consumed as Wstack[(h,k),c]=W[k,h*64+c]
// fused epilogue options: scale, bias, BN+ELU (mode 1), +resid, fp8 h8 snapshot,
// as/ad logits via u/v (butterfly fold), fused attentional pooling via attW.
__global__ __launch_bounds__(256)
void gemm_n64_mfma(const void* __restrict__ Araw, int lda, int a_is_bf16,
                   const float* __restrict__ W, int w_gat, int M, int K,
                   const float* __restrict__ bias, float scale,
                   float* __restrict__ C, int ldc, int mode,
                   const float* __restrict__ bn_g, const float* __restrict__ bn_b,
                   const float* __restrict__ bn_m, const float* __restrict__ bn_v,
                   const float* __restrict__ resid, int ldr,
                   unsigned char* __restrict__ h8_out,
                   const float* __restrict__ u, const float* __restrict__ v,
                   float* __restrict__ as_out, float* __restrict__ ad_out,
                   const float* __restrict__ attW, const float* __restrict__ attb,
                   const int* __restrict__ batch,
                   float* __restrict__ hg_acc, float* __restrict__ wsum_acc)
{
    __shared__ short Wt[64 * 264];           // max K=256 -> KP=264
    const int KP = K + 8;
    int tid  = threadIdx.x;
    int lane = tid & 63, wave = tid >> 6;
    int row0 = blockIdx.x * 64;
    int c15 = lane & 15, q = lane >> 4;

    {
        int n = tid & 63;
        for (int k = tid >> 6; k < K; k += 4) {
            int widx = w_gat ? ((k & 63) * 256 + (k >> 6) * 64 + n) : (k * 64 + n);
            Wt[n * KP + k] = f2bf(W[widx]);
        }
    }
    __syncthreads();

    int row = row0 + wave * 16 + c15;
    bool rok = row < M;

    f32x4 acc[4];
    #pragma unroll
    for (int st = 0; st < 4; ++st) acc[st] = (f32x4){0.f, 0.f, 0.f, 0.f};

    for (int k0 = 0; k0 < K; k0 += 32) {
        bf16x8 av;
        if (rok) {
            if (a_is_bf16) {
                av = *(const bf16x8*)((const unsigned short*)Araw
                                      + (size_t)row * lda + k0 + q * 8);
            } else {
                const float* ap = (const float*)Araw + (size_t)row * lda + k0 + q * 8;
                float4 a0 = *(const float4*)ap;
                float4 a1 = *(const float4*)(ap + 4);
                av[0] = f2bf(a0.x); av[1] = f2bf(a0.y); av[2] = f2bf(a0.z); av[3] = f2bf(a0.w);
                av[4] = f2bf(a1.x); av[5] = f2bf(a1.y); av[6] = f2bf(a1.z); av[7] = f2bf(a1.w);
            }
        } else {
            av = (bf16x8){0,0,0,0,0,0,0,0};
        }
        #pragma unroll
        for (int st = 0; st < 4; ++st) {
            bf16x8 bv = *(const bf16x8*)(Wt + (st * 16 + c15) * KP + k0 + q * 8);
            acc[st] = __builtin_amdgcn_mfma_f32_16x16x32_bf16(av, bv, acc[st], 0, 0, 0);
        }
    }

    #pragma unroll
    for (int st = 0; st < 4; ++st) {
        int col = st * 16 + c15;
        float bs = bias ? bias[col] : 0.f;
        float sg = 1.f, sb = 0.f;
        if (mode == 1) {
            sg = bn_g[col] / sqrtf(bn_v[col] + BNEPS);
            sb = bn_b[col] - bn_m[col] * sg;
        }
        #pragma unroll
        for (int r = 0; r < 4; ++r) {
            int orow = row0 + wave * 16 + q * 4 + r;
            if (orow >= M) continue;
            float vvv = acc[st][r] * scale + bs;
            if (mode == 1) {
                vvv = vvv * sg + sb;
                vvv = vvv > 0.f ? vvv : __expf(vvv) - 1.f;
            }
            if (resid) vvv += resid[(size_t)orow * ldr + col];
            acc[st][r] = vvv;
            if (C) C[(size_t)orow * ldc + col] = vvv;
        }
    }

    if (h8_out) {
        #pragma unroll
        for (int r = 0; r < 4; ++r) {
            int orow = row0 + wave * 16 + q * 4 + r;
            if (orow >= M) continue;
            unsigned char* hb = h8_out + (size_t)orow * 64 + c15;
            #pragma unroll
            for (int st = 0; st < 4; ++st)
                hb[st * 16] = f2fp8(acc[st][r]);
        }
    }

    if (u) {
        float uu[4][4], vv2[4][4];
        #pragma unroll
        for (int h = 0; h < 4; ++h)
            #pragma unroll
            for (int st = 0; st < 4; ++st) {
                uu[h][st]  = u[h * 64 + st * 16 + c15];
                vv2[h][st] = v[h * 64 + st * 16 + c15];
            }
        #pragma unroll
        for (int r = 0; r < 4; ++r) {
            int orow = row0 + wave * 16 + q * 4 + r;
            float pv[8];
            #pragma unroll
            for (int h = 0; h < 4; ++h) {
                pv[h]     = acc[0][r] * uu[h][0] + acc[1][r] * uu[h][1]
                          + acc[2][r] * uu[h][2] + acc[3][r] * uu[h][3];
                pv[4 + h] = acc[0][r] * vv2[h][0] + acc[1][r] * vv2[h][1]
                          + acc[2][r] * vv2[h][2] + acc[3][r] * vv2[h][3];
            }
            #pragma unroll
            for (int j = 0; j < 4; ++j) {
                float send = (c15 & 8) ? pv[j] : pv[j + 4];
                float keep = (c15 & 8) ? pv[j + 4] : pv[j];
                pv[j] = keep + __shfl_xor(send, 8);
            }
            #pragma unroll
            for (int j = 0; j < 2; ++j) {
                float send = (c15 & 4) ? pv[j] : pv[j + 2];
                float keep = (c15 & 4) ? pv[j + 2] : pv[j];
                pv[j] = keep + __shfl_xor(send, 4);
            }
            {
                float send = (c15 & 2) ? pv[0] : pv[1];
                float keep = (c15 & 2) ? pv[1] : pv[0];
                pv[0] = keep + __shfl_xor(send, 2);
            }
            pv[0] += __shfl_xor(pv[0], 1);
            if ((c15 & 1) == 0 && orow < M) {
                int jj = c15 >> 1;
                if (jj < 4) as_out[orow * 4 + jj] = pv[0];
                else        ad_out[orow * 4 + (jj - 4)] = pv[0];
            }
        }
    }

    // ---- fused attentional pooling: w = exp(h·attW + b); atomic per-graph sums ----
    if (attW) {
        float sa[4];
        #pragma unroll
        for (int st = 0; st < 4; ++st) sa[st] = attW[st * 16 + c15];
        float ab = attb[0];
        #pragma unroll
        for (int r = 0; r < 4; ++r) {
            int orow = row0 + wave * 16 + q * 4 + r;
            bool ok = orow < M;
            float ps = acc[0][r] * sa[0] + acc[1][r] * sa[1]
                     + acc[2][r] * sa[2] + acc[3][r] * sa[3];
            #pragma unroll
            for (int o = 1; o < 16; o <<= 1) ps += __shfl_xor(ps, o);
            float w = __expf(ps + ab);                 // every lane has its row's weight
            int g = ok ? batch[orow] : -1;
            // uniformity of graph id across the 4 q-lanes (stride 16)
            int mn = g, mx = g;
            { int t1 = __shfl_xor(mn, 16); mn = min(mn, t1); t1 = __shfl_xor(mx, 16); mx = max(mx, t1); }
            { int t1 = __shfl_xor(mn, 32); mn = min(mn, t1); t1 = __shfl_xor(mx, 32); mx = max(mx, t1); }
            bool uni = (mn == mx) && (mn >= 0);
            #pragma unroll
            for (int st = 0; st < 4; ++st) {
                float vv = ok ? acc[st][r] * w : 0.f;
                float vq = vv + __shfl_xor(vv, 16);
                vq += __shfl_xor(vq, 32);
                int col = st * 16 + c15;
                if (uni) {
                    if (q == 0) atomicAdd(&hg_acc[g * 64 + col], vq);
                } else if (ok) {
                    atomicAdd(&hg_acc[g * 64 + col], vv);
                }
            }
            float wv = (ok && c15 == 0) ? w : 0.f;
            float wq = wv + __shfl_xor(wv, 16);
            wq += __shfl_xor(wq, 32);
            if (uni) {
                if (q == 0 && c15 == 0) atomicAdd(&wsum_acc[g], wq);
            } else if (ok && c15 == 0) {
                atomicAdd(&wsum_acc[g], wv);
            }
        }
    }
}

// ---------- CSR build: histogram over dst ----------
__global__ __launch_bounds__(256)
void hist_kernel(const int* __restrict__ ei, int E, int N, int* __restrict__ counts)
{
    int e = blockIdx.x * blockDim.x + threadIdx.x;
    int Etot = E + N;
    if (e >= Etot) return;
    int d = (e < E) ? ei[E + e] : e - E;
    atomicAdd(&counts[d], 1);
}

// ---------- scan phase 1: per-block partial sums ----------
__global__ __launch_bounds__(256)
void scan_phase1(const int* __restrict__ counts, int N, int* __restrict__ blocksum)
{
    __shared__ int wsum[4];
    int tid = threadIdx.x, lane = tid & 63, wave = tid >> 6;
    int base = blockIdx.x * SCAN_CHUNK;
    int s = 0;
    #pragma unroll
    for (int j = 0; j < SCAN_CHUNK / 256; ++j) {
        int idx = base + tid + j * 256;
        if (idx < N) s += counts[idx];
    }
    #pragma unroll
    for (int o = 32; o; o >>= 1) s += __shfl_xor(s, o);
    if (lane == 0) wsum[wave] = s;
    __syncthreads();
    if (tid == 0) blocksum[blockIdx.x] = wsum[0] + wsum[1] + wsum[2] + wsum[3];
}

// ---------- scan phase 3 (merged with global prefix of block sums) ----------
__global__ __launch_bounds__(256)
void scan_phase3(const int* __restrict__ counts, int N, int nb,
                 const int* __restrict__ blocksum,
                 int* __restrict__ rowptr, int* __restrict__ cursor)
{
    __shared__ int wsum[4];
    __shared__ int pref[64];
    int tid = threadIdx.x, lane = tid & 63, wave = tid >> 6;

    if (wave == 0) {
        int v = (lane < nb) ? blocksum[lane] : 0;
        int incl = v;
        #pragma unroll
        for (int o = 1; o < 64; o <<= 1) {
            int t = __shfl_up(incl, o);
            if (lane >= o) incl += t;
        }
        pref[lane] = incl;
    }
    __syncthreads();
    int boff = blockIdx.x ? pref[blockIdx.x - 1] : 0;
    if (blockIdx.x == 0 && tid == 0) rowptr[N] = pref[nb - 1];

    int start = blockIdx.x * SCAN_CHUNK + tid * 8;
    int v[8];
    int s = 0;
    #pragma unroll
    for (int j = 0; j < 8; ++j) {
        v[j] = (start + j < N) ? counts[start + j] : 0;
        s += v[j];
    }
    int incl = s;
    #pragma unroll
    for (int o = 1; o < 64; o <<= 1) {
        int t = __shfl_up(incl, o);
        if (lane >= o) incl += t;
    }
    if (lane == 63) wsum[wave] = incl;
    __syncthreads();
    int woff = 0;
    #pragma unroll
    for (int w = 0; w < 4; ++w) if (w < wave) woff += wsum[w];
    int run = boff + woff + incl - s;
    #pragma unroll
    for (int j = 0; j < 8; ++j) {
        int idx = start + j;
        if (idx < N) { rowptr[idx] = run; cursor[idx] = run; }
        run += v[j];
    }
}

// ---------- CSR build: scatter ----------
__global__ __launch_bounds__(256)
void scatter_kernel(const int* __restrict__ ei, int E, int N,
                    int* __restrict__ cursor, int* __restrict__ csr_src)
{
    int e = blockIdx.x * blockDim.x + threadIdx.x;
    int Etot = E + N;
    if (e >= Etot) return;
    int s, d;
    if (e < E) { s = ei[e]; d = ei[E + e]; } else { s = d = e - E; }
    int pos = atomicAdd(&cursor[d], 1);
    csr_src[pos] = s;
}

// ---------- layer-0 GAT aggregation (fp8 256-ch message gather) ----------
__global__ __launch_bounds__(256)
void aggregate_kernel(const int* __restrict__ rowptr, const int* __restrict__ csr_src,
                      const float* __restrict__ as_n, const float* __restrict__ ad_n,
                      const unsigned char* __restrict__ xh8,
                      const float* __restrict__ bias,
                      unsigned short* __restrict__ outp, int N)
{
    int node = (blockIdx.x * blockDim.x + threadIdx.x) >> 6;
    int lane = threadIdx.x & 63;
    if (node >= N) return;
    int h = lane >> 4, li = lane & 15, grp = lane & 48;
    int e0 = rowptr[node], e1 = rowptr[node + 1];
    float adh = ad_n[node * 4 + h];
    unsigned laneoff = (unsigned)(lane * 4);   // 4 fp8 bytes per lane

    float4 acc = make_float4(0.f, 0.f, 0.f, 0.f);
    float wsum = 0.f;

    for (int base = e0; base < e1; base += 16) {
        int cnt = e1 - base; if (cnt > 16) cnt = 16;
        int s = 0; float w = 0.f;
        if (li < cnt) {
            s = csr_src[base + li];
            float l = as_n[s * 4 + h] + adh;
            l = fmaxf(l, NEG * l);
            w = __expf(l);
        }
        int k = 0;
        for (; k + 3 < cnt; k += 4) {
            float w0 = __shfl(w, grp + k),     w1 = __shfl(w, grp + k + 1);
            float w2 = __shfl(w, grp + k + 2), w3 = __shfl(w, grp + k + 3);
            int s0 = __shfl(s, grp + k),       s1 = __shfl(s, grp + k + 1);
            int s2 = __shfl(s, grp + k + 2),   s3 = __shfl(s, grp + k + 3);
            unsigned x0 = *(const unsigned*)(xh8 + ((unsigned)s0 * 256u + laneoff));
            unsigned x1 = *(const unsigned*)(xh8 + ((unsigned)s1 * 256u + laneoff));
            unsigned x2 = *(const unsigned*)(xh8 + ((unsigned)s2 * 256u + laneoff));
            unsigned x3 = *(const unsigned*)(xh8 + ((unsigned)s3 * 256u + laneoff));
            f32x2 l0 = __builtin_amdgcn_cvt_pk_f32_fp8((int)x0, false);
            f32x2 h0 = __builtin_amdgcn_cvt_pk_f32_fp8((int)x0, true);
            f32x2 l1 = __builtin_amdgcn_cvt_pk_f32_fp8((int)x1, false);
            f32x2 h1 = __builtin_amdgcn_cvt_pk_f32_fp8((int)x1, true);
            f32x2 l2 = __builtin_amdgcn_cvt_pk_f32_fp8((int)x2, false);
            f32x2 h2 = __builtin_amdgcn_cvt_pk_f32_fp8((int)x2, true);
            f32x2 l3 = __builtin_amdgcn_cvt_pk_f32_fp8((int)x3, false);
            f32x2 h3 = __builtin_amdgcn_cvt_pk_f32_fp8((int)x3, true);
            acc.x += w0 * l0.x; acc.y += w0 * l0.y; acc.z += w0 * h0.x; acc.w += w0 * h0.y;
            acc.x += w1 * l1.x; acc.y += w1 * l1.y; acc.z += w1 * h1.x; acc.w += w1 * h1.y;
            acc.x += w2 * l2.x; acc.y += w2 * l2.y; acc.z += w2 * h2.x; acc.w += w2 * h2.y;
            acc.x += w3 * l3.x; acc.y += w3 * l3.y; acc.z += w3 * h3.x; acc.w += w3 * h3.y;
            wsum += (w0 + w1) + (w2 + w3);
        }
        for (; k < cnt; ++k) {
            float wk = __shfl(w, grp + k);
            int sk = __shfl(s, grp + k);
            unsigned xv = *(const unsigned*)(xh8 + ((unsigned)sk * 256u + laneoff));
            f32x2 lo = __builtin_amdgcn_cvt_pk_f32_fp8((int)xv, false);
            f32x2 hi = __builtin_amdgcn_cvt_pk_f32_fp8((int)xv, true);
            acc.x += wk * lo.x; acc.y += wk * lo.y;
            acc.z += wk * hi.x; acc.w += wk * hi.y;
            wsum += wk;
        }
    }

    float rw = 1.f / wsum;
    float4 bs = *(const float4*)(bias + lane * 4);
    ushort4 pk;
    pk.x = (unsigned short)f2bf(acc.x * rw + bs.x);
    pk.y = (unsigned short)f2bf(acc.y * rw + bs.y);
    pk.z = (unsigned short)f2bf(acc.z * rw + bs.z);
    pk.w = (unsigned short)f2bf(acc.w * rw + bs.w);
    *(ushort4*)(outp + (size_t)node * 256 + lane * 4) = pk;
}

// ---------- layers 1-2 aggregation: 64B fp8 rows, proven mapping ----------
__global__ __launch_bounds__(256)
void aggregate_z(const int* __restrict__ rowptr, const int* __restrict__ csr_src,
                 const float* __restrict__ as_n, const float* __restrict__ ad_n,
                 const unsigned char* __restrict__ h8,
                 unsigned short* __restrict__ zout, int N)
{
    int node = (blockIdx.x * blockDim.x + threadIdx.x) >> 6;
    int lane = threadIdx.x & 63;
    if (node >= N) return;
    int h = lane >> 4, li = lane & 15, grp = lane & 48;
    int e0 = rowptr[node], e1 = rowptr[node + 1];
    float adh = ad_n[node * 4 + h];
    unsigned laneoff = (unsigned)(li * 4);     // 4 fp8 bytes within the 64B row

    float4 acc = make_float4(0.f, 0.f, 0.f, 0.f);
    float wsum = 0.f;

    for (int base = e0; base < e1; base += 16) {
        int cnt = e1 - base; if (cnt > 16) cnt = 16;
        int s = 0; float w = 0.f;
        if (li < cnt) {
            s = csr_src[base + li];
            float l = as_n[s * 4 + h] + adh;
            l = fmaxf(l, NEG * l);
            w = __expf(l);
        }
        int k = 0;
        for (; k + 3 < cnt; k += 4) {
            float w0 = __shfl(w, grp + k),     w1 = __shfl(w, grp + k + 1);
            float w2 = __shfl(w, grp + k + 2), w3 = __shfl(w, grp + k + 3);
            int s0 = __shfl(s, grp + k),       s1 = __shfl(s, grp + k + 1);
            int s2 = __shfl(s, grp + k + 2),   s3 = __shfl(s, grp + k + 3);
            unsigned x0 = *(const unsigned*)(h8 + ((unsigned)s0 * 64u + laneoff));
            unsigned x1 = *(const unsigned*)(h8 + ((unsigned)s1 * 64u + laneoff));
            unsigned x2 = *(const unsigned*)(h8 + ((unsigned)s2 * 64u + laneoff));
            unsigned x3 = *(const unsigned*)(h8 + ((unsigned)s3 * 64u + laneoff));
            f32x2 l0 = __builtin_amdgcn_cvt_pk_f32_fp8((int)x0, false);
            f32x2 h0 = __builtin_amdgcn_cvt_pk_f32_fp8((int)x0, true);
            f32x2 l1 = __builtin_amdgcn_cvt_pk_f32_fp8((int)x1, false);
            f32x2 h1 = __builtin_amdgcn_cvt_pk_f32_fp8((int)x1, true);
            f32x2 l2 = __builtin_amdgcn_cvt_pk_f32_fp8((int)x2, false);
            f32x2 h2 = __builtin_amdgcn_cvt_pk_f32_fp8((int)x2, true);
            f32x2 l3 = __builtin_amdgcn_cvt_pk_f32_fp8((int)x3, false);
            f32x2 h3 = __builtin_amdgcn_cvt_pk_f32_fp8((int)x3, true);
            acc.x += w0 * l0.x; acc.y += w0 * l0.y; acc.z += w0 * h0.x; acc.w += w0 * h0.y;
            acc.x += w1 * l1.x; acc.y += w1 * l1.y; acc.z += w1 * h1.x; acc.w += w1 * h1.y;
            acc.x += w2 * l2.x; acc.y += w2 * l2.y; acc.z += w2 * h2.x; acc.w += w2 * h2.y;
            acc.x += w3 * l3.x; acc.y += w3 * l3.y; acc.z += w3 * h3.x; acc.w += w3 * h3.y;
            wsum += (w0 + w1) + (w2 + w3);
        }
        for (; k < cnt; ++k) {
            float wk = __shfl(w, grp + k);
            int sk = __shfl(s, grp + k);
            unsigned xv = *(const unsigned*)(h8 + ((unsigned)sk * 64u + laneoff));
            f32x2 lo = __builtin_amdgcn_cvt_pk_f32_fp8((int)xv, false);
            f32x2 hi = __builtin_amdgcn_cvt_pk_f32_fp8((int)xv, true);
            acc.x += wk * lo.x; acc.y += wk * lo.y;
            acc.z += wk * hi.x; acc.w += wk * hi.y;
            wsum += wk;
        }
    }

    float rw = 1.f / wsum;
    ushort4 pk;
    pk.x = (unsigned short)f2bf(acc.x * rw);
    pk.y = (unsigned short)f2bf(acc.y * rw);
    pk.z = (unsigned short)f2bf(acc.z * rw);
    pk.w = (unsigned short)f2bf(acc.w * rw);
    *(ushort4*)(zout + (size_t)node * 256 + h * 64 + li * 4) = pk;
}

// ---------- classifier head ----------
__global__ void cls_kernel(const float* __restrict__ hg_acc,
                           const float* __restrict__ wsum_acc,
                           const float* __restrict__ W1, const float* __restrict__ b1,
                           const float* __restrict__ W2, const float* __restrict__ b2,
                           float* __restrict__ out)
{
    int g = blockIdx.x, t = threadIdx.x;  // 32 threads
    __shared__ float z[32];
    __shared__ float h[64];
    float wsum = wsum_acc[g];
    float rw = (wsum > 0.f) ? 1.f / wsum : 0.f;
    h[t] = hg_acc[g * 64 + t] * rw;
    h[t + 32] = hg_acc[g * 64 + t + 32] * rw;
    __syncthreads();
    float acc = b1[t];
    for (int k = 0; k < 64; ++k) acc += h[k] * W1[k * 32 + t];
    z[t] = fmaxf(acc, 0.f);
    __syncthreads();
    if (t < 2) {
        float o = b2[t];
        for (int j = 0; j < 32; ++j) o += z[j] * W2[j * 2 + t];
        out[g * 2 + t] = o;
    }
}

extern "C" void kernel_launch(void* const* d_in, const int* in_sizes, int n_in,
                              void* d_out, int out_size, void* d_ws, size_t ws_size,
                              hipStream_t stream)
{
    const float* x        = (const float*)d_in[0];
    const int*   ei       = (const int*)d_in[1];
    const int*   batch    = (const int*)d_in[2];
    const float* conv0_W  = (const float*)d_in[3];
    const float* conv0_as = (const float*)d_in[4];
    const float* conv0_ad = (const float*)d_in[5];
    const float* conv0_b  = (const float*)d_in[6];
    const float* pre0_W   = (const float*)d_in[7];
    const float* pre0_b   = (const float*)d_in[8];
    const float* convs_W  = (const float*)d_in[9];
    const float* convs_as = (const float*)d_in[10];
    const float* convs_ad = (const float*)d_in[11];
    const float* convs_b  = (const float*)d_in[12];
    const float* bn_g     = (const float*)d_in[13];
    const float* bn_b     = (const float*)d_in[14];
    const float* bn_m     = (const float*)d_in[15];
    const float* bn_v     = (const float*)d_in[16];
    const float* jump_W   = (const float*)d_in[17];
    const float* jump_b   = (const float*)d_in[18];
    const float* att_W    = (const float*)d_in[19];
    const float* att_b    = (const float*)d_in[20];
    const float* cls_W1   = (const float*)d_in[21];
    const float* cls_b1   = (const float*)d_in[22];
    const float* cls_W2   = (const float*)d_in[23];
    const float* cls_b2   = (const float*)d_in[24];
    float* out = (float*)d_out;

    const int N = in_sizes[0] / 128;   // 50000
    const int E = in_sizes[1] / 2;     // 400000
    const int Etot = E + N;
    const int nb = (N + SCAN_CHUNK - 1) / SCAN_CHUNK;   // 25 <= 64

    // workspace layout
    float* ws      = (float*)d_ws;
    unsigned char* xh8      = (unsigned char*)ws;            // layer0: N*256 fp8; then h8a N*64 fp8 (aliased)
    unsigned short* h256_bf = (unsigned short*)ws + (size_t)N * 256;  // N*256 bf16 (L0 out_cat / z)
    float* repsAll = (float*)(h256_bf + (size_t)N * 256);   // N*192 f32
    float* as_n    = repsAll + (size_t)N * 192;             // N*4
    float* ad_n    = as_n + (size_t)N * 4;                  // N*4
    float* hg_acc  = ad_n + (size_t)N * 4;                  // 64*64
    float* wsum_acc= hg_acc + NGRAPH * 64;                  // 64
    int*   rowptr  = (int*)(wsum_acc + NGRAPH);             // N+1
    int*   cursor  = rowptr + (N + 1);                      // N
    int*   counts  = cursor + N;                            // N
    int*   csr_src = counts + N;                            // Etot
    int*   gstart  = csr_src + Etot;                        // 65
    int*   blocksum = gstart + (NGRAPH + 1);                // 64
    float* uv      = (float*)(blocksum + 64);               // u[2][4][64]+v[2][4][64] = 1024
    float* as2     = uv + 1024;                             // N*4 (L2 logits)
    float* ad2     = as2 + (size_t)N * 4;                   // N*4
    unsigned char* h8b = (unsigned char*)(ad2 + (size_t)N * 4);  // N*64 fp8
    unsigned char* h8a = xh8;                               // N*64 fp8 (reuse xh8 region)

    dim3 blk(256);
    int node_wave_blocks = (N + 3) / 4;
    int edge_blocks      = (Etot + 255) / 256;
    int row_blocks       = (N + 63) / 64;

    // ---------------- init + CSR build ----------------
    init_kernel<<<64, blk, 0, stream>>>(batch, N, counts, gstart, hg_acc, wsum_acc,
                                        convs_W, convs_as, convs_ad, uv);
    hist_kernel<<<edge_blocks, blk, 0, stream>>>(ei, E, N, counts);
    scan_phase1<<<nb, blk, 0, stream>>>(counts, N, blocksum);
    scan_phase3<<<nb, blk, 0, stream>>>(counts, N, nb, blocksum, rowptr, cursor);
    scatter_kernel<<<edge_blocks, blk, 0, stream>>>(ei, E, N, cursor, csr_src);

    // ---------------- layer 0 ----------------
    {
        dim3 g1(row_blocks, 4);
        gemm_xh_mfma<<<g1, blk, 0, stream>>>(x, 128, conv0_W, 256, N, 128,
                                             conv0_as, conv0_ad, as_n, ad_n, xh8);
        aggregate_kernel<<<node_wave_blocks, blk, 0, stream>>>(
            rowptr, csr_src, as_n, ad_n, xh8, conv0_b, h256_bf, N);
        // pre0: h256 -> h1 (BN+ELU), fused: h8a snapshot + layer-1 as/ad logits
        gemm_n64_mfma<<<row_blocks, blk, 0, stream>>>(
            h256_bf, 256, 1, pre0_W, 0, N, 256, pre0_b, 1.f,
            repsAll, 192, 1, bn_g, bn_b, bn_m, bn_v,
            nullptr, 0, h8a, uv, uv + 512, as_n, ad_n,
            nullptr, nullptr, nullptr, nullptr, nullptr);
    }

    // ---------------- layer 1 ----------------
    aggregate_z<<<node_wave_blocks, blk, 0, stream>>>(rowptr, csr_src, as_n, ad_n,
                                                      h8a, h256_bf, N);
    gemm_n64_mfma<<<row_blocks, blk, 0, stream>>>(
        h256_bf, 256, 1, convs_W, 1, N, 256, convs_b, 0.25f,
        repsAll + 64, 192, 1, bn_g + 64, bn_b + 64, bn_m + 64, bn_v + 64,
        repsAll, 192, h8b, uv + 256, uv + 512 + 256, as2, ad2,
        nullptr, nullptr, nullptr, nullptr, nullptr);

    // ---------------- layer 2 ----------------
    aggregate_z<<<node_wave_blocks, blk, 0, stream>>>(rowptr, csr_src, as2, ad2,
                                                      h8b, h256_bf, N);
    gemm_n64_mfma<<<row_blocks, blk, 0, stream>>>(
        h256_bf, 256, 1, convs_W + (size_t)64 * 256, 1, N, 256, convs_b + 64, 0.25f,
        repsAll + 128, 192, 1, bn_g + 128, bn_b + 128, bn_m + 128, bn_v + 128,
        repsAll + 64, 192, nullptr, nullptr, nullptr, nullptr, nullptr,
        nullptr, nullptr, nullptr, nullptr, nullptr);

    // ---------------- JK projection + fused attentional pooling ----------------
    gemm_n64_mfma<<<row_blocks, blk, 0, stream>>>(
        repsAll, 192, 0, jump_W, 0, N, 192, jump_b, 1.f,
        nullptr, 64, 0, nullptr, nullptr, nullptr, nullptr,
        nullptr, 0, nullptr, nullptr, nullptr, nullptr, nullptr,
        att_W, att_b, batch, hg_acc, wsum_acc);

    // ---------------- classifier ----------------
    cls_kernel<<<NGRAPH, 32, 0, stream>>>(hg_acc, wsum_acc, cls_W1, cls_b1,
                                          cls_W2, cls_b2, out);
}

// Round 6
// 354.513 us; speedup vs baseline: 1.2769x; 1.2224x over previous
//
#include <hip/hip_runtime.h>
#include <hip/hip_bf16.h>
#include <math.h>

#define NEG 0.2f
#define BNEPS 1e-5f
#define NGRAPH 64
#define SCAN_CHUNK 2048

typedef short bf16x8 __attribute__((ext_vector_type(8)));            // 8 bf16 (4 VGPRs)
typedef float f32x4  __attribute__((ext_vector_type(4)));            // MFMA accumulator
typedef float f32x2  __attribute__((ext_vector_type(2)));            // fp8 cvt result

__device__ __forceinline__ float bf2f(unsigned short u) {
    return __uint_as_float(((unsigned)u) << 16);
}
__device__ __forceinline__ short f2bf(float f) {
    return (short)__bfloat16_as_ushort(__float2bfloat16(f));
}
__device__ __forceinline__ unsigned char f2fp8(float f) {
    // OCP e4m3 on gfx950; pack (f,f) and take low byte
    int pk = __builtin_amdgcn_cvt_pk_fp8_f32(f, f, 0, false);
    return (unsigned char)(pk & 0xFF);
}

// ---------- init: zero counts, pool accs, gstart; block 1: u/v = W_h @ att ----------
__global__ __launch_bounds__(256)
void init_kernel(const int* __restrict__ batch, int N,
                 int* __restrict__ counts, int* __restrict__ gstart,
                 float* __restrict__ hg_acc, float* __restrict__ wsum_acc,
                 const float* __restrict__ convs_W,
                 const float* __restrict__ convs_as, const float* __restrict__ convs_ad,
                 float* __restrict__ uv)
{
    int idx = blockIdx.x * 256 + threadIdx.x;
    for (int i = idx; i < N; i += gridDim.x * 256) counts[i] = 0;
    if (blockIdx.x == 0) {
        int t = threadIdx.x;
        for (int i = t; i < NGRAPH * 64; i += 256) hg_acc[i] = 0.f;
        if (t < NGRAPH) wsum_acc[t] = 0.f;
        if (t <= NGRAPH) {
            int lo = 0, hi = N;
            while (lo < hi) {
                int mid = (lo + hi) >> 1;
                if (batch[mid] < t) lo = mid + 1; else hi = mid;
            }
            gstart[t] = lo;
        }
    }
    if (blockIdx.x == 1) {
        // uv layout: u[2][4][64] then v[2][4][64]
        int t = threadIdx.x;
        int h = t >> 6, k = t & 63;
        for (int i = 0; i < 2; ++i) {
            const float* Wr  = convs_W + (size_t)i * 64 * 256 + k * 256 + h * 64;
            const float* av  = convs_as + i * 256 + h * 64;
            const float* dv  = convs_ad + i * 256 + h * 64;
            float su = 0.f, sv = 0.f;
            for (int c = 0; c < 64; ++c) { su += Wr[c] * av[c]; sv += Wr[c] * dv[c]; }
            uv[i * 256 + h * 64 + k]       = su;
            uv[512 + i * 256 + h * 64 + k] = sv;
        }
    }
}

// ---------- MFMA bf16 GEMM for layer-0 xh: C8[M,256] = fp8(A @ W) + att dots ----------
__global__ __launch_bounds__(256)
void gemm_xh_mfma(const float* __restrict__ A, int lda,
                  const float* __restrict__ W, int Nc, int M, int K,
                  const float* __restrict__ att_s, const float* __restrict__ att_d,
                  float* __restrict__ as_out, float* __restrict__ ad_out,
                  unsigned char* __restrict__ C8)
{
    __shared__ short Wt[64 * 136];           // max K=128 -> KP=136
    const int KP = K + 8;
    int tid  = threadIdx.x;
    int lane = tid & 63, wave = tid >> 6;
    int row0 = blockIdx.x * 64;
    int colb = blockIdx.y * 64;
    int c15 = lane & 15, q = lane >> 4;

    {
        int n = tid & 63;
        for (int k = tid >> 6; k < K; k += 4)
            Wt[n * KP + k] = f2bf(W[(size_t)k * Nc + colb + n]);
    }
    __syncthreads();

    int row = row0 + wave * 16 + c15;
    bool rok = row < M;
    const float* arow = A + (size_t)row * lda + q * 8;

    f32x4 acc[4];
    #pragma unroll
    for (int st = 0; st < 4; ++st) acc[st] = (f32x4){0.f, 0.f, 0.f, 0.f};

    for (int k0 = 0; k0 < K; k0 += 32) {
        bf16x8 av;
        if (rok) {
            float4 a0 = *(const float4*)(arow + k0);
            float4 a1 = *(const float4*)(arow + k0 + 4);
            av[0] = f2bf(a0.x); av[1] = f2bf(a0.y); av[2] = f2bf(a0.z); av[3] = f2bf(a0.w);
            av[4] = f2bf(a1.x); av[5] = f2bf(a1.y); av[6] = f2bf(a1.z); av[7] = f2bf(a1.w);
        } else {
            av = (bf16x8){0,0,0,0,0,0,0,0};
        }
        #pragma unroll
        for (int st = 0; st < 4; ++st) {
            bf16x8 bv = *(const bf16x8*)(Wt + (st * 16 + c15) * KP + k0 + q * 8);
            acc[st] = __builtin_amdgcn_mfma_f32_16x16x32_bf16(av, bv, acc[st], 0, 0, 0);
        }
    }

    #pragma unroll
    for (int r = 0; r < 4; ++r) {
        int orow = row0 + wave * 16 + q * 4 + r;
        if (orow >= M) continue;
        unsigned char* cb = C8 + (size_t)orow * 256 + colb + c15;
        #pragma unroll
        for (int st = 0; st < 4; ++st)
            cb[st * 16] = f2fp8(acc[st][r]);
    }
    float sa[4], da[4];
    #pragma unroll
    for (int st = 0; st < 4; ++st) {
        sa[st] = att_s[colb + st * 16 + c15];
        da[st] = att_d[colb + st * 16 + c15];
    }
    #pragma unroll
    for (int r = 0; r < 4; ++r) {
        float ps = acc[0][r] * sa[0] + acc[1][r] * sa[1] + acc[2][r] * sa[2] + acc[3][r] * sa[3];
        float pd = acc[0][r] * da[0] + acc[1][r] * da[1] + acc[2][r] * da[2] + acc[3][r] * da[3];
        #pragma unroll
        for (int o = 1; o < 16; o <<= 1) {
            ps += __shfl_xor(ps, o);
            pd += __shfl_xor(pd, o);
        }
        int orow = row0 + wave * 16 + q * 4 + r;
        if (c15 == 0 && orow < M) {
            as_out[orow * 4 + blockIdx.y] = ps;
            ad_out[orow * 4 + blockIdx.y] = pd;
        }
    }
}

// ---------- MFMA bf16 GEMM, Nc=64 ----------
// w_gat=1: W is convs_W (64,256) consumed as Wstack[(h,k),c]=W[k,h*64+c]
// fused epilogue options: scale, bias, BN+ELU (mode 1), +resid, fp8 h8 snapshot,
// as/ad logits via u/v (butterfly fold), fused attentional pooling via attW
// (block-reduced atomics: LDS tree -> 64 atomics per block per graph).
__global__ __launch_bounds__(256)
void gemm_n64_mfma(const void* __restrict__ Araw, int lda, int a_is_bf16,
                   const float* __restrict__ W, int w_gat, int M, int K,
                   const float* __restrict__ bias, float scale,
                   float* __restrict__ C, int ldc, int mode,
                   const float* __restrict__ bn_g, const float* __restrict__ bn_b,
                   const float* __restrict__ bn_m, const float* __restrict__ bn_v,
                   const float* __restrict__ resid, int ldr,
                   unsigned char* __restrict__ h8_out,
                   const float* __restrict__ u, const float* __restrict__ v,
                   float* __restrict__ as_out, float* __restrict__ ad_out,
                   const float* __restrict__ attW, const float* __restrict__ attb,
                   const int* __restrict__ batch,
                   float* __restrict__ hg_acc, float* __restrict__ wsum_acc)
{
    __shared__ short Wt[64 * 264];           // max K=256 -> KP=264 (reused as redbuf)
    const int KP = K + 8;
    int tid  = threadIdx.x;
    int lane = tid & 63, wave = tid >> 6;
    int row0 = blockIdx.x * 64;
    int c15 = lane & 15, q = lane >> 4;

    {
        int n = tid & 63;
        for (int k = tid >> 6; k < K; k += 4) {
            int widx = w_gat ? ((k & 63) * 256 + (k >> 6) * 64 + n) : (k * 64 + n);
            Wt[n * KP + k] = f2bf(W[widx]);
        }
    }
    __syncthreads();

    int row = row0 + wave * 16 + c15;
    bool rok = row < M;

    f32x4 acc[4];
    #pragma unroll
    for (int st = 0; st < 4; ++st) acc[st] = (f32x4){0.f, 0.f, 0.f, 0.f};

    for (int k0 = 0; k0 < K; k0 += 32) {
        bf16x8 av;
        if (rok) {
            if (a_is_bf16) {
                av = *(const bf16x8*)((const unsigned short*)Araw
                                      + (size_t)row * lda + k0 + q * 8);
            } else {
                const float* ap = (const float*)Araw + (size_t)row * lda + k0 + q * 8;
                float4 a0 = *(const float4*)ap;
                float4 a1 = *(const float4*)(ap + 4);
                av[0] = f2bf(a0.x); av[1] = f2bf(a0.y); av[2] = f2bf(a0.z); av[3] = f2bf(a0.w);
                av[4] = f2bf(a1.x); av[5] = f2bf(a1.y); av[6] = f2bf(a1.z); av[7] = f2bf(a1.w);
            }
        } else {
            av = (bf16x8){0,0,0,0,0,0,0,0};
        }
        #pragma unroll
        for (int st = 0; st < 4; ++st) {
            bf16x8 bv = *(const bf16x8*)(Wt + (st * 16 + c15) * KP + k0 + q * 8);
            acc[st] = __builtin_amdgcn_mfma_f32_16x16x32_bf16(av, bv, acc[st], 0, 0, 0);
        }
    }

    #pragma unroll
    for (int st = 0; st < 4; ++st) {
        int col = st * 16 + c15;
        float bs = bias ? bias[col] : 0.f;
        float sg = 1.f, sb = 0.f;
        if (mode == 1) {
            sg = bn_g[col] / sqrtf(bn_v[col] + BNEPS);
            sb = bn_b[col] - bn_m[col] * sg;
        }
        #pragma unroll
        for (int r = 0; r < 4; ++r) {
            int orow = row0 + wave * 16 + q * 4 + r;
            if (orow >= M) continue;
            float vvv = acc[st][r] * scale + bs;
            if (mode == 1) {
                vvv = vvv * sg + sb;
                vvv = vvv > 0.f ? vvv : __expf(vvv) - 1.f;
            }
            if (resid) vvv += resid[(size_t)orow * ldr + col];
            acc[st][r] = vvv;
            if (C) C[(size_t)orow * ldc + col] = vvv;
        }
    }

    if (h8_out) {
        #pragma unroll
        for (int r = 0; r < 4; ++r) {
            int orow = row0 + wave * 16 + q * 4 + r;
            if (orow >= M) continue;
            unsigned char* hb = h8_out + (size_t)orow * 64 + c15;
            #pragma unroll
            for (int st = 0; st < 4; ++st)
                hb[st * 16] = f2fp8(acc[st][r]);
        }
    }

    if (u) {
        float uu[4][4], vv2[4][4];
        #pragma unroll
        for (int h = 0; h < 4; ++h)
            #pragma unroll
            for (int st = 0; st < 4; ++st) {
                uu[h][st]  = u[h * 64 + st * 16 + c15];
                vv2[h][st] = v[h * 64 + st * 16 + c15];
            }
        #pragma unroll
        for (int r = 0; r < 4; ++r) {
            int orow = row0 + wave * 16 + q * 4 + r;
            float pv[8];
            #pragma unroll
            for (int h = 0; h < 4; ++h) {
                pv[h]     = acc[0][r] * uu[h][0] + acc[1][r] * uu[h][1]
                          + acc[2][r] * uu[h][2] + acc[3][r] * uu[h][3];
                pv[4 + h] = acc[0][r] * vv2[h][0] + acc[1][r] * vv2[h][1]
                          + acc[2][r] * vv2[h][2] + acc[3][r] * vv2[h][3];
            }
            #pragma unroll
            for (int j = 0; j < 4; ++j) {
                float send = (c15 & 8) ? pv[j] : pv[j + 4];
                float keep = (c15 & 8) ? pv[j + 4] : pv[j];
                pv[j] = keep + __shfl_xor(send, 8);
            }
            #pragma unroll
            for (int j = 0; j < 2; ++j) {
                float send = (c15 & 4) ? pv[j] : pv[j + 2];
                float keep = (c15 & 4) ? pv[j + 2] : pv[j];
                pv[j] = keep + __shfl_xor(send, 4);
            }
            {
                float send = (c15 & 2) ? pv[0] : pv[1];
                float keep = (c15 & 2) ? pv[1] : pv[0];
                pv[0] = keep + __shfl_xor(send, 2);
            }
            pv[0] += __shfl_xor(pv[0], 1);
            if ((c15 & 1) == 0 && orow < M) {
                int jj = c15 >> 1;
                if (jj < 4) as_out[orow * 4 + jj] = pv[0];
                else        ad_out[orow * 4 + (jj - 4)] = pv[0];
            }
        }
    }

    // ---- fused attentional pooling with block-level reduction ----
    if (attW) {
        float sa[4];
        #pragma unroll
        for (int st = 0; st < 4; ++st) sa[st] = attW[st * 16 + c15];
        float ab = attb[0];
        float wrow[4];
        int   grow[4];
        #pragma unroll
        for (int r = 0; r < 4; ++r) {
            int orow = row0 + wave * 16 + q * 4 + r;
            bool ok = orow < M;
            float ps = acc[0][r] * sa[0] + acc[1][r] * sa[1]
                     + acc[2][r] * sa[2] + acc[3][r] * sa[3];
            #pragma unroll
            for (int o = 1; o < 16; o <<= 1) ps += __shfl_xor(ps, o);
            wrow[r] = ok ? __expf(ps + ab) : 0.f;
            grow[r] = ok ? batch[orow] : -1;
        }
        int lastrow = row0 + 63; if (lastrow >= M) lastrow = M - 1;
        int gmin = batch[row0 < M ? row0 : M - 1];
        int gmax = batch[lastrow];
        float* red = (float*)Wt;   // [64][4] col-partials + [4] wsum partials
        __syncthreads();           // all waves done reading Wt
        for (int g = gmin; g <= gmax; ++g) {
            float cs[4] = {0.f, 0.f, 0.f, 0.f};
            float wsl = 0.f;
            #pragma unroll
            for (int r = 0; r < 4; ++r) {
                if (grow[r] == g) {
                    #pragma unroll
                    for (int st = 0; st < 4; ++st) cs[st] += acc[st][r] * wrow[r];
                    wsl += wrow[r];
                }
            }
            // reduce over the 4 q-lanes (stride 16)
            #pragma unroll
            for (int st = 0; st < 4; ++st) {
                cs[st] += __shfl_xor(cs[st], 16);
                cs[st] += __shfl_xor(cs[st], 32);
            }
            wsl += __shfl_xor(wsl, 16);
            wsl += __shfl_xor(wsl, 32);
            if (q == 0) {
                #pragma unroll
                for (int st = 0; st < 4; ++st)
                    red[(st * 16 + c15) * 4 + wave] = cs[st];
                if (c15 == 0) red[256 + wave] = wsl;
            }
            __syncthreads();
            if (tid < 64) {
                float vv = red[tid * 4] + red[tid * 4 + 1]
                         + red[tid * 4 + 2] + red[tid * 4 + 3];
                if (vv != 0.f) atomicAdd(&hg_acc[g * 64 + tid], vv);
            } else if (tid == 64) {
                float t = red[256] + red[257] + red[258] + red[259];
                if (t != 0.f) atomicAdd(&wsum_acc[g], t);
            }
            __syncthreads();
        }
    }
}

// ---------- CSR build: histogram over dst ----------
__global__ __launch_bounds__(256)
void hist_kernel(const int* __restrict__ ei, int E, int N, int* __restrict__ counts)
{
    int e = blockIdx.x * blockDim.x + threadIdx.x;
    int Etot = E + N;
    if (e >= Etot) return;
    int d = (e < E) ? ei[E + e] : e - E;
    atomicAdd(&counts[d], 1);
}

// ---------- scan phase 1: per-block partial sums ----------
__global__ __launch_bounds__(256)
void scan_phase1(const int* __restrict__ counts, int N, int* __restrict__ blocksum)
{
    __shared__ int wsum[4];
    int tid = threadIdx.x, lane = tid & 63, wave = tid >> 6;
    int base = blockIdx.x * SCAN_CHUNK;
    int s = 0;
    #pragma unroll
    for (int j = 0; j < SCAN_CHUNK / 256; ++j) {
        int idx = base + tid + j * 256;
        if (idx < N) s += counts[idx];
    }
    #pragma unroll
    for (int o = 32; o; o >>= 1) s += __shfl_xor(s, o);
    if (lane == 0) wsum[wave] = s;
    __syncthreads();
    if (tid == 0) blocksum[blockIdx.x] = wsum[0] + wsum[1] + wsum[2] + wsum[3];
}

// ---------- scan phase 3 (merged with global prefix of block sums) ----------
__global__ __launch_bounds__(256)
void scan_phase3(const int* __restrict__ counts, int N, int nb,
                 const int* __restrict__ blocksum,
                 int* __restrict__ rowptr, int* __restrict__ cursor)
{
    __shared__ int wsum[4];
    __shared__ int pref[64];
    int tid = threadIdx.x, lane = tid & 63, wave = tid >> 6;

    if (wave == 0) {
        int v = (lane < nb) ? blocksum[lane] : 0;
        int incl = v;
        #pragma unroll
        for (int o = 1; o < 64; o <<= 1) {
            int t = __shfl_up(incl, o);
            if (lane >= o) incl += t;
        }
        pref[lane] = incl;
    }
    __syncthreads();
    int boff = blockIdx.x ? pref[blockIdx.x - 1] : 0;
    if (blockIdx.x == 0 && tid == 0) rowptr[N] = pref[nb - 1];

    int start = blockIdx.x * SCAN_CHUNK + tid * 8;
    int v[8];
    int s = 0;
    #pragma unroll
    for (int j = 0; j < 8; ++j) {
        v[j] = (start + j < N) ? counts[start + j] : 0;
        s += v[j];
    }
    int incl = s;
    #pragma unroll
    for (int o = 1; o < 64; o <<= 1) {
        int t = __shfl_up(incl, o);
        if (lane >= o) incl += t;
    }
    if (lane == 63) wsum[wave] = incl;
    __syncthreads();
    int woff = 0;
    #pragma unroll
    for (int w = 0; w < 4; ++w) if (w < wave) woff += wsum[w];
    int run = boff + woff + incl - s;
    #pragma unroll
    for (int j = 0; j < 8; ++j) {
        int idx = start + j;
        if (idx < N) { rowptr[idx] = run; cursor[idx] = run; }
        run += v[j];
    }
}

// ---------- CSR build: scatter ----------
__global__ __launch_bounds__(256)
void scatter_kernel(const int* __restrict__ ei, int E, int N,
                    int* __restrict__ cursor, int* __restrict__ csr_src)
{
    int e = blockIdx.x * blockDim.x + threadIdx.x;
    int Etot = E + N;
    if (e >= Etot) return;
    int s, d;
    if (e < E) { s = ei[e]; d = ei[E + e]; } else { s = d = e - E; }
    int pos = atomicAdd(&cursor[d], 1);
    csr_src[pos] = s;
}

// ---------- layer-0 GAT aggregation (fp8 256-ch message gather) ----------
__global__ __launch_bounds__(256)
void aggregate_kernel(const int* __restrict__ rowptr, const int* __restrict__ csr_src,
                      const float* __restrict__ as_n, const float* __restrict__ ad_n,
                      const unsigned char* __restrict__ xh8,
                      const float* __restrict__ bias,
                      unsigned short* __restrict__ outp, int N)
{
    int node = (blockIdx.x * blockDim.x + threadIdx.x) >> 6;
    int lane = threadIdx.x & 63;
    if (node >= N) return;
    int h = lane >> 4, li = lane & 15, grp = lane & 48;
    int e0 = rowptr[node], e1 = rowptr[node + 1];
    float adh = ad_n[node * 4 + h];
    unsigned laneoff = (unsigned)(lane * 4);   // 4 fp8 bytes per lane

    float4 acc = make_float4(0.f, 0.f, 0.f, 0.f);
    float wsum = 0.f;

    for (int base = e0; base < e1; base += 16) {
        int cnt = e1 - base; if (cnt > 16) cnt = 16;
        int s = 0; float w = 0.f;
        if (li < cnt) {
            s = csr_src[base + li];
            float l = as_n[s * 4 + h] + adh;
            l = fmaxf(l, NEG * l);
            w = __expf(l);
        }
        int k = 0;
        for (; k + 3 < cnt; k += 4) {
            float w0 = __shfl(w, grp + k),     w1 = __shfl(w, grp + k + 1);
            float w2 = __shfl(w, grp + k + 2), w3 = __shfl(w, grp + k + 3);
            int s0 = __shfl(s, grp + k),       s1 = __shfl(s, grp + k + 1);
            int s2 = __shfl(s, grp + k + 2),   s3 = __shfl(s, grp + k + 3);
            unsigned x0 = *(const unsigned*)(xh8 + ((unsigned)s0 * 256u + laneoff));
            unsigned x1 = *(const unsigned*)(xh8 + ((unsigned)s1 * 256u + laneoff));
            unsigned x2 = *(const unsigned*)(xh8 + ((unsigned)s2 * 256u + laneoff));
            unsigned x3 = *(const unsigned*)(xh8 + ((unsigned)s3 * 256u + laneoff));
            f32x2 l0 = __builtin_amdgcn_cvt_pk_f32_fp8((int)x0, false);
            f32x2 h0 = __builtin_amdgcn_cvt_pk_f32_fp8((int)x0, true);
            f32x2 l1 = __builtin_amdgcn_cvt_pk_f32_fp8((int)x1, false);
            f32x2 h1 = __builtin_amdgcn_cvt_pk_f32_fp8((int)x1, true);
            f32x2 l2 = __builtin_amdgcn_cvt_pk_f32_fp8((int)x2, false);
            f32x2 h2 = __builtin_amdgcn_cvt_pk_f32_fp8((int)x2, true);
            f32x2 l3 = __builtin_amdgcn_cvt_pk_f32_fp8((int)x3, false);
            f32x2 h3 = __builtin_amdgcn_cvt_pk_f32_fp8((int)x3, true);
            acc.x += w0 * l0.x; acc.y += w0 * l0.y; acc.z += w0 * h0.x; acc.w += w0 * h0.y;
            acc.x += w1 * l1.x; acc.y += w1 * l1.y; acc.z += w1 * h1.x; acc.w += w1 * h1.y;
            acc.x += w2 * l2.x; acc.y += w2 * l2.y; acc.z += w2 * h2.x; acc.w += w2 * h2.y;
            acc.x += w3 * l3.x; acc.y += w3 * l3.y; acc.z += w3 * h3.x; acc.w += w3 * h3.y;
            wsum += (w0 + w1) + (w2 + w3);
        }
        for (; k < cnt; ++k) {
            float wk = __shfl(w, grp + k);
            int sk = __shfl(s, grp + k);
            unsigned xv = *(const unsigned*)(xh8 + ((unsigned)sk * 256u + laneoff));
            f32x2 lo = __builtin_amdgcn_cvt_pk_f32_fp8((int)xv, false);
            f32x2 hi = __builtin_amdgcn_cvt_pk_f32_fp8((int)xv, true);
            acc.x += wk * lo.x; acc.y += wk * lo.y;
            acc.z += wk * hi.x; acc.w += wk * hi.y;
            wsum += wk;
        }
    }

    float rw = 1.f / wsum;
    float4 bs = *(const float4*)(bias + lane * 4);
    ushort4 pk;
    pk.x = (unsigned short)f2bf(acc.x * rw + bs.x);
    pk.y = (unsigned short)f2bf(acc.y * rw + bs.y);
    pk.z = (unsigned short)f2bf(acc.z * rw + bs.z);
    pk.w = (unsigned short)f2bf(acc.w * rw + bs.w);
    *(ushort4*)(outp + (size_t)node * 256 + lane * 4) = pk;
}

// ---------- layers 1-2 aggregation: 64B fp8 rows, proven mapping ----------
__global__ __launch_bounds__(256)
void aggregate_z(const int* __restrict__ rowptr, const int* __restrict__ csr_src,
                 const float* __restrict__ as_n, const float* __restrict__ ad_n,
                 const unsigned char* __restrict__ h8,
                 unsigned short* __restrict__ zout, int N)
{
    int node = (blockIdx.x * blockDim.x + threadIdx.x) >> 6;
    int lane = threadIdx.x & 63;
    if (node >= N) return;
    int h = lane >> 4, li = lane & 15, grp = lane & 48;
    int e0 = rowptr[node], e1 = rowptr[node + 1];
    float adh = ad_n[node * 4 + h];
    unsigned laneoff = (unsigned)(li * 4);     // 4 fp8 bytes within the 64B row

    float4 acc = make_float4(0.f, 0.f, 0.f, 0.f);
    float wsum = 0.f;

    for (int base = e0; base < e1; base += 16) {
        int cnt = e1 - base; if (cnt > 16) cnt = 16;
        int s = 0; float w = 0.f;
        if (li < cnt) {
            s = csr_src[base + li];
            float l = as_n[s * 4 + h] + adh;
            l = fmaxf(l, NEG * l);
            w = __expf(l);
        }
        int k = 0;
        for (; k + 3 < cnt; k += 4) {
            float w0 = __shfl(w, grp + k),     w1 = __shfl(w, grp + k + 1);
            float w2 = __shfl(w, grp + k + 2), w3 = __shfl(w, grp + k + 3);
            int s0 = __shfl(s, grp + k),       s1 = __shfl(s, grp + k + 1);
            int s2 = __shfl(s, grp + k + 2),   s3 = __shfl(s, grp + k + 3);
            unsigned x0 = *(const unsigned*)(h8 + ((unsigned)s0 * 64u + laneoff));
            unsigned x1 = *(const unsigned*)(h8 + ((unsigned)s1 * 64u + laneoff));
            unsigned x2 = *(const unsigned*)(h8 + ((unsigned)s2 * 64u + laneoff));
            unsigned x3 = *(const unsigned*)(h8 + ((unsigned)s3 * 64u + laneoff));
            f32x2 l0 = __builtin_amdgcn_cvt_pk_f32_fp8((int)x0, false);
            f32x2 h0 = __builtin_amdgcn_cvt_pk_f32_fp8((int)x0, true);
            f32x2 l1 = __builtin_amdgcn_cvt_pk_f32_fp8((int)x1, false);
            f32x2 h1 = __builtin_amdgcn_cvt_pk_f32_fp8((int)x1, true);
            f32x2 l2 = __builtin_amdgcn_cvt_pk_f32_fp8((int)x2, false);
            f32x2 h2 = __builtin_amdgcn_cvt_pk_f32_fp8((int)x2, true);
            f32x2 l3 = __builtin_amdgcn_cvt_pk_f32_fp8((int)x3, false);
            f32x2 h3 = __builtin_amdgcn_cvt_pk_f32_fp8((int)x3, true);
            acc.x += w0 * l0.x; acc.y += w0 * l0.y; acc.z += w0 * h0.x; acc.w += w0 * h0.y;
            acc.x += w1 * l1.x; acc.y += w1 * l1.y; acc.z += w1 * h1.x; acc.w += w1 * h1.y;
            acc.x += w2 * l2.x; acc.y += w2 * l2.y; acc.z += w2 * h2.x; acc.w += w2 * h2.y;
            acc.x += w3 * l3.x; acc.y += w3 * l3.y; acc.z += w3 * h3.x; acc.w += w3 * h3.y;
            wsum += (w0 + w1) + (w2 + w3);
        }
        for (; k < cnt; ++k) {
            float wk = __shfl(w, grp + k);
            int sk = __shfl(s, grp + k);
            unsigned xv = *(const unsigned*)(h8 + ((unsigned)sk * 64u + laneoff));
            f32x2 lo = __builtin_amdgcn_cvt_pk_f32_fp8((int)xv, false);
            f32x2 hi = __builtin_amdgcn_cvt_pk_f32_fp8((int)xv, true);
            acc.x += wk * lo.x; acc.y += wk * lo.y;
            acc.z += wk * hi.x; acc.w += wk * hi.y;
            wsum += wk;
        }
    }

    float rw = 1.f / wsum;
    ushort4 pk;
    pk.x = (unsigned short)f2bf(acc.x * rw);
    pk.y = (unsigned short)f2bf(acc.y * rw);
    pk.z = (unsigned short)f2bf(acc.z * rw);
    pk.w = (unsigned short)f2bf(acc.w * rw);
    *(ushort4*)(zout + (size_t)node * 256 + h * 64 + li * 4) = pk;
}

// ---------- classifier head ----------
__global__ void cls_kernel(const float* __restrict__ hg_acc,
                           const float* __restrict__ wsum_acc,
                           const float* __restrict__ W1, const float* __restrict__ b1,
                           const float* __restrict__ W2, const float* __restrict__ b2,
                           float* __restrict__ out)
{
    int g = blockIdx.x, t = threadIdx.x;  // 32 threads
    __shared__ float z[32];
    __shared__ float h[64];
    float wsum = wsum_acc[g];
    float rw = (wsum > 0.f) ? 1.f / wsum : 0.f;
    h[t] = hg_acc[g * 64 + t] * rw;
    h[t + 32] = hg_acc[g * 64 + t + 32] * rw;
    __syncthreads();
    float acc = b1[t];
    for (int k = 0; k < 64; ++k) acc += h[k] * W1[k * 32 + t];
    z[t] = fmaxf(acc, 0.f);
    __syncthreads();
    if (t < 2) {
        float o = b2[t];
        for (int j = 0; j < 32; ++j) o += z[j] * W2[j * 2 + t];
        out[g * 2 + t] = o;
    }
}

extern "C" void kernel_launch(void* const* d_in, const int* in_sizes, int n_in,
                              void* d_out, int out_size, void* d_ws, size_t ws_size,
                              hipStream_t stream)
{
    const float* x        = (const float*)d_in[0];
    const int*   ei       = (const int*)d_in[1];
    const int*   batch    = (const int*)d_in[2];
    const float* conv0_W  = (const float*)d_in[3];
    const float* conv0_as = (const float*)d_in[4];
    const float* conv0_ad = (const float*)d_in[5];
    const float* conv0_b  = (const float*)d_in[6];
    const float* pre0_W   = (const float*)d_in[7];
    const float* pre0_b   = (const float*)d_in[8];
    const float* convs_W  = (const float*)d_in[9];
    const float* convs_as = (const float*)d_in[10];
    const float* convs_ad = (const float*)d_in[11];
    const float* convs_b  = (const float*)d_in[12];
    const float* bn_g     = (const float*)d_in[13];
    const float* bn_b     = (const float*)d_in[14];
    const float* bn_m     = (const float*)d_in[15];
    const float* bn_v     = (const float*)d_in[16];
    const float* jump_W   = (const float*)d_in[17];
    const float* jump_b   = (const float*)d_in[18];
    const float* att_W    = (const float*)d_in[19];
    const float* att_b    = (const float*)d_in[20];
    const float* cls_W1   = (const float*)d_in[21];
    const float* cls_b1   = (const float*)d_in[22];
    const float* cls_W2   = (const float*)d_in[23];
    const float* cls_b2   = (const float*)d_in[24];
    float* out = (float*)d_out;

    const int N = in_sizes[0] / 128;   // 50000
    const int E = in_sizes[1] / 2;     // 400000
    const int Etot = E + N;
    const int nb = (N + SCAN_CHUNK - 1) / SCAN_CHUNK;   // 25 <= 64

    // workspace layout
    float* ws      = (float*)d_ws;
    unsigned char* xh8      = (unsigned char*)ws;            // layer0: N*256 fp8; then h8a N*64 fp8 (aliased)
    unsigned short* h256_bf = (unsigned short*)ws + (size_t)N * 256;  // N*256 bf16 (L0 out_cat / z)
    float* repsAll = (float*)(h256_bf + (size_t)N * 256);   // N*192 f32
    float* as_n    = repsAll + (size_t)N * 192;             // N*4
    float* ad_n    = as_n + (size_t)N * 4;                  // N*4
    float* hg_acc  = ad_n + (size_t)N * 4;                  // 64*64
    float* wsum_acc= hg_acc + NGRAPH * 64;                  // 64
    int*   rowptr  = (int*)(wsum_acc + NGRAPH);             // N+1
    int*   cursor  = rowptr + (N + 1);                      // N
    int*   counts  = cursor + N;                            // N
    int*   csr_src = counts + N;                            // Etot
    int*   gstart  = csr_src + Etot;                        // 65
    int*   blocksum = gstart + (NGRAPH + 1);                // 64
    float* uv      = (float*)(blocksum + 64);               // u[2][4][64]+v[2][4][64] = 1024
    float* as2     = uv + 1024;                             // N*4 (L2 logits)
    float* ad2     = as2 + (size_t)N * 4;                   // N*4
    unsigned char* h8b = (unsigned char*)(ad2 + (size_t)N * 4);  // N*64 fp8
    unsigned char* h8a = xh8;                               // N*64 fp8 (reuse xh8 region)

    dim3 blk(256);
    int node_wave_blocks = (N + 3) / 4;
    int edge_blocks      = (Etot + 255) / 256;
    int row_blocks       = (N + 63) / 64;

    // ---------------- init + CSR build ----------------
    init_kernel<<<64, blk, 0, stream>>>(batch, N, counts, gstart, hg_acc, wsum_acc,
                                        convs_W, convs_as, convs_ad, uv);
    hist_kernel<<<edge_blocks, blk, 0, stream>>>(ei, E, N, counts);
    scan_phase1<<<nb, blk, 0, stream>>>(counts, N, blocksum);
    scan_phase3<<<nb, blk, 0, stream>>>(counts, N, nb, blocksum, rowptr, cursor);
    scatter_kernel<<<edge_blocks, blk, 0, stream>>>(ei, E, N, cursor, csr_src);

    // ---------------- layer 0 ----------------
    {
        dim3 g1(row_blocks, 4);
        gemm_xh_mfma<<<g1, blk, 0, stream>>>(x, 128, conv0_W, 256, N, 128,
                                             conv0_as, conv0_ad, as_n, ad_n, xh8);
        aggregate_kernel<<<node_wave_blocks, blk, 0, stream>>>(
            rowptr, csr_src, as_n, ad_n, xh8, conv0_b, h256_bf, N);
        // pre0: h256 -> h1 (BN+ELU), fused: h8a snapshot + layer-1 as/ad logits
        gemm_n64_mfma<<<row_blocks, blk, 0, stream>>>(
            h256_bf, 256, 1, pre0_W, 0, N, 256, pre0_b, 1.f,
            repsAll, 192, 1, bn_g, bn_b, bn_m, bn_v,
            nullptr, 0, h8a, uv, uv + 512, as_n, ad_n,
            nullptr, nullptr, nullptr, nullptr, nullptr);
    }

    // ---------------- layer 1 ----------------
    aggregate_z<<<node_wave_blocks, blk, 0, stream>>>(rowptr, csr_src, as_n, ad_n,
                                                      h8a, h256_bf, N);
    gemm_n64_mfma<<<row_blocks, blk, 0, stream>>>(
        h256_bf, 256, 1, convs_W, 1, N, 256, convs_b, 0.25f,
        repsAll + 64, 192, 1, bn_g + 64, bn_b + 64, bn_m + 64, bn_v + 64,
        repsAll, 192, h8b, uv + 256, uv + 512 + 256, as2, ad2,
        nullptr, nullptr, nullptr, nullptr, nullptr);

    // ---------------- layer 2 ----------------
    aggregate_z<<<node_wave_blocks, blk, 0, stream>>>(rowptr, csr_src, as2, ad2,
                                                      h8b, h256_bf, N);
    gemm_n64_mfma<<<row_blocks, blk, 0, stream>>>(
        h256_bf, 256, 1, convs_W + (size_t)64 * 256, 1, N, 256, convs_b + 64, 0.25f,
        repsAll + 128, 192, 1, bn_g + 128, bn_b + 128, bn_m + 128, bn_v + 128,
        repsAll + 64, 192, nullptr, nullptr, nullptr, nullptr, nullptr,
        nullptr, nullptr, nullptr, nullptr, nullptr);

    // ---------------- JK projection + fused attentional pooling ----------------
    gemm_n64_mfma<<<row_blocks, blk, 0, stream>>>(
        repsAll, 192, 0, jump_W, 0, N, 192, jump_b, 1.f,
        nullptr, 64, 0, nullptr, nullptr, nullptr, nullptr,
        nullptr, 0, nullptr, nullptr, nullptr, nullptr, nullptr,
        att_W, att_b, batch, hg_acc, wsum_acc);

    // ---------------- classifier ----------------
    cls_kernel<<<NGRAPH, 32, 0, stream>>>(hg_acc, wsum_acc, cls_W1, cls_b1,
                                          cls_W2, cls_b2, out);
}